// Round 6
// baseline (199.560 us; speedup 1.0000x reference)
//
#include <hip/hip_runtime.h>
#include <stdint.h>

#define E_       8
#define D_       1024
#define DFFN_    2048
#define T_       8192
#define TK_      16384
#define CAP_     16896
#define NBR_     64        // TK_/256 rank blocks
#define MAXT_    144       // max 128-row tiles

// workspace layout (bytes)
#define WS_SEL      0u          // TK_*4
#define WS_COUNTS   0x10000u    // 8*4
#define WS_CUMP     0x10100u    // 9*4
#define WS_TOTALS   0x10200u    // [0]=total_padded [1]=nTiles
#define WS_BLKCNT   0x10300u    // NBR_*8*4
#define WS_BLKOFF   0x10B00u    // NBR_*8*4
#define WS_TILES    0x11300u    // MAXT_*4
#define WS_ROWSRC   0x12000u    // CAP_*4
#define WS_XPAD     0x23000u    // CAP_*1024*2 = 34603008
#define WS_W1T      (0x23000u + 34603008u)  // 16384*1024*2

typedef __bf16 bf16x8 __attribute__((ext_vector_type(8)));
typedef float  f32x4  __attribute__((ext_vector_type(4)));

#define VMCNT(N) asm volatile("s_waitcnt vmcnt(" #N ")" ::: "memory")
#define BAR()    asm volatile("s_barrier" ::: "memory")

__device__ __forceinline__ unsigned short f2bf(float f) {
  union { float f; uint32_t u; } v; v.f = f;
  return (unsigned short)((v.u + 0x7fffu + ((v.u >> 16) & 1u)) >> 16);
}

// ---------------- 1. router: top-2 expert ids (no global atomics) ----------------
__global__ __launch_bounds__(256) void k_router(const float* __restrict__ x,
                                                const float* __restrict__ wr,
                                                int* __restrict__ sel) {
  __shared__ float lwr[E_ * D_];
  for (int i = threadIdx.x; i < E_ * D_ / 4; i += 256)
    ((float4*)lwr)[i] = ((const float4*)wr)[i];
  __syncthreads();
  int wave = threadIdx.x >> 6, lane = threadIdx.x & 63;

  for (int tk = 0; tk < 4; ++tk) {
    int t = blockIdx.x * 16 + wave * 4 + tk;
    double acc[E_];
#pragma unroll
    for (int e = 0; e < E_; ++e) acc[e] = 0.0;
    const float4* xr = (const float4*)(x + (size_t)t * D_);
#pragma unroll
    for (int j = 0; j < 4; ++j) {
      float4 v = xr[j * 64 + lane];
      int dbase = j * 256 + lane * 4;
#pragma unroll
      for (int e = 0; e < E_; ++e) {
        float4 w = *(const float4*)(lwr + e * D_ + dbase);
        acc[e] += (double)v.x * w.x + (double)v.y * w.y +
                  (double)v.z * w.z + (double)v.w * w.w;
      }
    }
#pragma unroll
    for (int e = 0; e < E_; ++e) {
      acc[e] += __shfl_xor(acc[e], 1, 64);
      acc[e] += __shfl_xor(acc[e], 2, 64);
      acc[e] += __shfl_xor(acc[e], 4, 64);
    }
    double s01 = (lane & 1) ? acc[1] : acc[0];
    double s23 = (lane & 1) ? acc[3] : acc[2];
    double s45 = (lane & 1) ? acc[5] : acc[4];
    double s67 = (lane & 1) ? acc[7] : acc[6];
    double t0 = (lane & 2) ? s23 : s01;
    double t1 = (lane & 2) ? s67 : s45;
    double u  = (lane & 4) ? t1 : t0;
    u += __shfl_xor(u, 8, 64);
    u += __shfl_xor(u, 16, 64);
    u += __shfl_xor(u, 32, 64);
    double lg[E_];
#pragma unroll
    for (int e = 0; e < E_; ++e) lg[e] = __shfl(u, e, 64);
    int e1 = 0; double b1 = lg[0];
#pragma unroll
    for (int e = 1; e < E_; ++e) if (lg[e] > b1) { b1 = lg[e]; e1 = e; }
    int e2 = (e1 == 0) ? 1 : 0; double b2 = lg[e2];
#pragma unroll
    for (int e = 0; e < E_; ++e) if (e != e1 && lg[e] > b2) { b2 = lg[e]; e2 = e; }
    if (lane == 0) {
      sel[2 * t]     = e1;
      sel[2 * t + 1] = e2;
    }
  }
}

// ---------------- 2. per-block expert histograms ----------------
__global__ __launch_bounds__(256) void k_blkcnt(const int* __restrict__ sel,
                                                int* __restrict__ blkCnt) {
  __shared__ int cnt[E_];
  if (threadIdx.x < E_) cnt[threadIdx.x] = 0;
  __syncthreads();
  atomicAdd(&cnt[sel[blockIdx.x * 256 + threadIdx.x]], 1);
  __syncthreads();
  if (threadIdx.x < E_) blkCnt[blockIdx.x * E_ + threadIdx.x] = cnt[threadIdx.x];
}

// ---------------- 3. tiny scans + 128-row tile table (1 block) ----------------
__global__ void k_scan(const int* __restrict__ blkCnt,
                       int* __restrict__ counts,
                       int* __restrict__ cum_p, int* __restrict__ totals,
                       int* __restrict__ blkOff, int* __restrict__ tiles) {
  int tid = threadIdx.x;
  if (tid < E_) {
    int run = 0;
    for (int b = 0; b < NBR_; ++b) {
      blkOff[b * E_ + tid] = run;
      run += blkCnt[b * E_ + tid];
    }
    counts[tid] = run;
  }
  __syncthreads();
  if (tid == 0) {
    int cp = 0, nt = 0;
    cum_p[0] = 0;
    for (int e = 0; e < E_; ++e) {
      int gs = (counts[e] + 63) / 64 * 64;
      int r = 0;
      while (r < gs) {
        int m = (gs - r >= 128) ? 128 : 64;
        tiles[nt++] = (cp + r) | (e << 20) | ((m == 128) ? (1 << 28) : 0);
        r += m;
      }
      cp += gs;
      cum_p[e + 1] = cp;
    }
    totals[0] = cp;
    totals[1] = nt;
  }
}

// ---------------- 4. stable rank -> row_src ----------------
__global__ __launch_bounds__(256) void k_rowsrc(const int* __restrict__ sel,
                                                const int* __restrict__ cum_p,
                                                const int* __restrict__ blkOff,
                                                int* __restrict__ row_src) {
  __shared__ int se[256];
  int i = blockIdx.x * 256 + threadIdx.x;
  int e = sel[i];
  se[threadIdx.x] = e;
  __syncthreads();
  int r = 0;
  for (int j = 0; j < threadIdx.x; ++j) r += (se[j] == e);
  row_src[cum_p[e] + blkOff[blockIdx.x * E_ + e] + r] = i >> 1;
}

// ---------------- 5. scatter x -> padded bf16 rows ----------------
__global__ __launch_bounds__(256) void k_scatter(const float* __restrict__ x,
                                                 const int* __restrict__ row_src,
                                                 unsigned short* __restrict__ xp) {
  int row = blockIdx.x;
  int src = row_src[row];
  ushort4 o;
  if (src >= 0) {
    float4 v = ((const float4*)(x + (size_t)src * D_))[threadIdx.x];
    o.x = f2bf(v.x); o.y = f2bf(v.y); o.z = f2bf(v.z); o.w = f2bf(v.w);
  } else {
    o.x = 0; o.y = 0; o.z = 0; o.w = 0;
  }
  ((ushort4*)(xp + (size_t)row * D_))[threadIdx.x] = o;
}

// ---------------- 6. w1 [d][16384] f32 -> w1t [n][1024] bf16 ----------------
__global__ __launch_bounds__(256) void k_w1conv(const float* __restrict__ w1,
                                                unsigned short* __restrict__ w1t) {
  __shared__ unsigned short lds[64][258];
  int n0 = blockIdx.x * 256, d0 = blockIdx.y * 64;
  int tid = threadIdx.x;
  int rIn = tid >> 6, c4 = tid & 63;
#pragma unroll
  for (int p = 0; p < 16; ++p) {
    int row = p * 4 + rIn;
    float4 v = *(const float4*)(w1 + (size_t)(d0 + row) * 16384 + n0 + c4 * 4);
    lds[row][c4 * 4 + 0] = f2bf(v.x);
    lds[row][c4 * 4 + 1] = f2bf(v.y);
    lds[row][c4 * 4 + 2] = f2bf(v.z);
    lds[row][c4 * 4 + 3] = f2bf(v.w);
  }
  __syncthreads();
  int d2 = (tid & 15) * 4, nn = tid >> 4;
#pragma unroll
  for (int q = 0; q < 16; ++q) {
    int n = q * 16 + nn;
    ushort4 o;
    o.x = lds[d2 + 0][n]; o.y = lds[d2 + 1][n];
    o.z = lds[d2 + 2][n]; o.w = lds[d2 + 3][n];
    *(ushort4*)(w1t + (size_t)(n0 + n) * 1024 + d0 + d2) = o;
  }
}

// ---------------- 7. grouped GEMM: 128x128, BK=64, dbuf 64KiB, 2 blocks/CU ----------------
// LDS per buffer: [128 rows][64 bf16] (128B rows), swizzled: byte_in_row ^= (row&7)<<4.
// 4 waves/block; 2 co-resident blocks per CU (m114 cross-block overlap hides the
// per-tile vmcnt drain and the f32 epilogue). Sync = one {vmcnt(0); s_barrier}/tile.

__device__ __forceinline__ void stage32(const unsigned short* gbase, // (row0, k0)
                                        unsigned short* ldsq,        // region base
                                        int tid) {
  int rr = tid >> 3;                                   // 0..31: row within region
  int co = ((tid & 7) ^ (rr & 7)) << 3;                // elem offset (inverse swizzle)
  const unsigned short* src = gbase + (size_t)rr * 1024 + co;
  unsigned short* dst = ldsq + ((tid >> 6) << 9);      // wave*512 elems; HW adds lane*16B
  __builtin_amdgcn_global_load_lds(
      (const __attribute__((address_space(1))) void*)src,
      (__attribute__((address_space(3))) void*)dst, 16, 0, 0);
}

#define READ_A(dst, KS)                                                         \
  {                                                                             \
    const unsigned short* p_ = Acur + (wr * 64 + lane15) * 64;                  \
    int co_ = (((KS) * 64 + g16) ^ swz) >> 1;                                   \
    _Pragma("unroll") for (int mi = 0; mi < 4; ++mi)                            \
      dst[mi] = *(const bf16x8*)(p_ + mi * 1024 + co_);                         \
  }

#define READ_B(dst, KS)                                                         \
  {                                                                             \
    const unsigned short* p_ = Bcur + (wc * 64 + lane15) * 64;                  \
    int co_ = (((KS) * 64 + g16) ^ swz) >> 1;                                   \
    _Pragma("unroll") for (int ni = 0; ni < 4; ++ni)                            \
      dst[ni] = *(const bf16x8*)(p_ + ni * 1024 + co_);                         \
  }

#define MFMA16(AV, BV)                                                          \
  __builtin_amdgcn_s_setprio(1);                                                \
  _Pragma("unroll") for (int mi = 0; mi < 4; ++mi)                              \
    _Pragma("unroll") for (int ni = 0; ni < 4; ++ni)                            \
      acc[mi][ni] = __builtin_amdgcn_mfma_f32_16x16x32_bf16(                    \
          AV[mi], BV[ni], acc[mi][ni], 0, 0, 0);                                \
  __builtin_amdgcn_s_setprio(0);

__global__ __launch_bounds__(256, 2) void k_gemm(const unsigned short* __restrict__ xp,
                                                 const unsigned short* __restrict__ w1t,
                                                 const int* __restrict__ tiles,
                                                 const int* __restrict__ totals,
                                                 float* __restrict__ out) {
  // T1: bijective XCD chunking (2304 = 8*288); mtile-major inside a chunk so the
  // 16 ny-blocks sharing an A-panel land on one XCD back-to-back.
  int P = blockIdx.y * MAXT_ + blockIdx.x;
  int L = (P & 7) * (MAXT_ * 16 / 8) + (P >> 3);
  int mtile = L >> 4, ny = L & 15;
  if (mtile >= totals[1]) return;

  int info = tiles[mtile];
  int rowBase = info & 0xFFFFF;
  int e = (info >> 20) & 0xFF;
  int mLimit = ((info >> 28) & 1) ? 128 : 64;

  __shared__ unsigned short As[2 * 128 * 64];
  __shared__ unsigned short Bs[2 * 128 * 64];

  int tid = threadIdx.x, wave = tid >> 6, lane = tid & 63;
  int lane15 = lane & 15;
  int g16 = (lane >> 4) * 16;          // byte offset of k-group
  int swz = (lane15 & 7) << 4;         // read-side swizzle (bytes)
  int wr = wave >> 1, wc = wave & 1;

  const unsigned short* Ag = xp + (size_t)rowBase * D_;
  const unsigned short* Bg = w1t + ((size_t)e * DFFN_ + (size_t)ny * 128) * D_;

  f32x4 acc[4][4];
#pragma unroll
  for (int i = 0; i < 4; ++i)
#pragma unroll
    for (int j = 0; j < 4; ++j) acc[i][j] = (f32x4){0.f, 0.f, 0.f, 0.f};

  // prologue: stage K-tile 0 into buf0
  stage32(Ag + 0 * 32768, As + 0 * 2048, tid);
  stage32(Ag + 1 * 32768, As + 1 * 2048, tid);
  stage32(Ag + 2 * 32768, As + 2 * 2048, tid);
  stage32(Ag + 3 * 32768, As + 3 * 2048, tid);
  stage32(Bg + 0 * 32768, Bs + 0 * 2048, tid);
  stage32(Bg + 1 * 32768, Bs + 1 * 2048, tid);
  stage32(Bg + 2 * 32768, Bs + 2 * 2048, tid);
  stage32(Bg + 3 * 32768, Bs + 3 * 2048, tid);
  VMCNT(0);
  BAR();

  for (int t = 0; t < 16; ++t) {
    const unsigned short* Acur = As + (t & 1) * 8192;
    const unsigned short* Bcur = Bs + (t & 1) * 8192;
    unsigned short* Anx = As + ((t + 1) & 1) * 8192;
    unsigned short* Bnx = Bs + ((t + 1) & 1) * 8192;
    int k1 = (t + 1) * 64;             // next K-tile elem offset
    bool st = (t < 15);

    bf16x8 a0[4], b0[4], a1[4], b1[4];

    // issue next-tile staging early (writes only buf^1: no intra-tile hazard)
    if (st) {
      stage32(Ag + 0 * 32768 + k1, Anx + 0 * 2048, tid);
      stage32(Ag + 1 * 32768 + k1, Anx + 1 * 2048, tid);
      stage32(Ag + 2 * 32768 + k1, Anx + 2 * 2048, tid);
      stage32(Ag + 3 * 32768 + k1, Anx + 3 * 2048, tid);
    }
    READ_A(a0, 0);
    READ_B(b0, 0);
    if (st) {
      stage32(Bg + 0 * 32768 + k1, Bnx + 0 * 2048, tid);
      stage32(Bg + 1 * 32768 + k1, Bnx + 1 * 2048, tid);
      stage32(Bg + 2 * 32768 + k1, Bnx + 2 * 2048, tid);
      stage32(Bg + 3 * 32768 + k1, Bnx + 3 * 2048, tid);
    }
    MFMA16(a0, b0);
    READ_A(a1, 1);
    READ_B(b1, 1);
    MFMA16(a1, b1);

    // K-tile boundary: next tile's 8 stages retired, all waves past reads of buf
    VMCNT(0);
    BAR();
  }

  // epilogue: C layout col=lane&15, row=(lane>>4)*4+q
#pragma unroll
  for (int mi = 0; mi < 4; ++mi) {
    int mrow = wr * 64 + mi * 16;
    if (mrow >= mLimit) continue;
    int r0 = rowBase + mrow + (lane >> 4) * 4;
#pragma unroll
    for (int ni = 0; ni < 4; ++ni) {
      int col = ny * 128 + wc * 64 + ni * 16 + lane15;
      f32x4 v = acc[mi][ni];
#pragma unroll
      for (int q = 0; q < 4; ++q)
        out[(size_t)(r0 + q) * DFFN_ + col] = v[q];
    }
  }
}

// ---------------- 8. zero tail rows >= total_padded ----------------
__global__ __launch_bounds__(256) void k_ztail(const int* __restrict__ totals,
                                               float* __restrict__ out) {
  int row = TK_ + blockIdx.x;          // 16384 .. 16895
  if (row < totals[0]) return;
  float4 z = {0.f, 0.f, 0.f, 0.f};
  float4* o = (float4*)(out + (size_t)row * DFFN_);
  o[threadIdx.x] = z;
  o[threadIdx.x + 256] = z;
}

extern "C" void kernel_launch(void* const* d_in, const int* in_sizes, int n_in,
                              void* d_out, int out_size, void* d_ws, size_t ws_size,
                              hipStream_t stream) {
  const float* x  = (const float*)d_in[0];
  const float* wr = (const float*)d_in[1];
  const float* w1 = (const float*)d_in[2];
  float* out = (float*)d_out;
  char* ws = (char*)d_ws;

  int* sel     = (int*)(ws + WS_SEL);
  int* counts  = (int*)(ws + WS_COUNTS);
  int* cum_p   = (int*)(ws + WS_CUMP);
  int* totals  = (int*)(ws + WS_TOTALS);
  int* blkCnt  = (int*)(ws + WS_BLKCNT);
  int* blkOff  = (int*)(ws + WS_BLKOFF);
  int* tiles   = (int*)(ws + WS_TILES);
  int* row_src = (int*)(ws + WS_ROWSRC);
  unsigned short* xp  = (unsigned short*)(ws + WS_XPAD);
  unsigned short* w1t = (unsigned short*)(ws + WS_W1T);

  hipMemsetAsync(row_src, 0xFF, CAP_ * sizeof(int), stream);

  k_w1conv<<<dim3(64, 16), 256, 0, stream>>>(w1, w1t);
  k_router<<<T_ / 16, 256, 0, stream>>>(x, wr, sel);
  k_blkcnt<<<NBR_, 256, 0, stream>>>(sel, blkCnt);
  k_scan<<<1, 64, 0, stream>>>(blkCnt, counts, cum_p, totals, blkOff, tiles);
  k_rowsrc<<<NBR_, 256, 0, stream>>>(sel, cum_p, blkOff, row_src);
  k_scatter<<<CAP_, 256, 0, stream>>>(x, row_src, xp);
  k_gemm<<<dim3(MAXT_, 16), 256, 0, stream>>>(xp, w1t, tiles, totals, out);
  k_ztail<<<512, 256, 0, stream>>>(totals, out);
}

// Round 7
// 166.743 us; speedup vs baseline: 1.1968x; 1.1968x over previous
//
#include <hip/hip_runtime.h>
#include <stdint.h>

#define E_       8
#define D_       1024
#define DFFN_    2048
#define T_       8192
#define TK_      16384
#define CAP_     16896
#define NBR_     64        // TK_/256 rank blocks
#define MAXT_    144       // max 128-row tiles

// workspace layout (bytes)
#define WS_SEL      0u          // TK_*4
#define WS_COUNTS   0x10000u    // 8*4
#define WS_CUMP     0x10100u    // 9*4
#define WS_TOTALS   0x10200u    // [0]=total_padded [1]=nTiles
#define WS_BLKCNT   0x10300u    // NBR_*8*4
#define WS_BLKOFF   0x10B00u    // NBR_*8*4
#define WS_TILES    0x11300u    // MAXT_*4
#define WS_ROWSRC   0x12000u    // CAP_*4
#define WS_XBF      0x23000u    // T_*1024*2 = 16777216
#define WS_W1T      (0x23000u + 34603008u)  // 16384*1024*2 (offset kept from prior rounds)

typedef __bf16 bf16x8 __attribute__((ext_vector_type(8)));
typedef float  f32x4  __attribute__((ext_vector_type(4)));

__device__ __forceinline__ unsigned short f2bf(float f) {
  union { float f; uint32_t u; } v; v.f = f;
  return (unsigned short)((v.u + 0x7fffu + ((v.u >> 16) & 1u)) >> 16);
}

// ---------------- 1. router: top-2 expert ids + bf16 cast of x ----------------
__global__ __launch_bounds__(256) void k_router(const float* __restrict__ x,
                                                const float* __restrict__ wr,
                                                int* __restrict__ sel,
                                                unsigned short* __restrict__ xbf) {
  __shared__ float lwr[E_ * D_];
  for (int i = threadIdx.x; i < E_ * D_ / 4; i += 256)
    ((float4*)lwr)[i] = ((const float4*)wr)[i];
  __syncthreads();
  int wave = threadIdx.x >> 6, lane = threadIdx.x & 63;

  for (int tk = 0; tk < 4; ++tk) {
    int t = blockIdx.x * 16 + wave * 4 + tk;
    double acc[E_];
#pragma unroll
    for (int e = 0; e < E_; ++e) acc[e] = 0.0;
    const float4* xr = (const float4*)(x + (size_t)t * D_);
    ushort4* xw = (ushort4*)(xbf + (size_t)t * D_);
#pragma unroll
    for (int j = 0; j < 4; ++j) {
      float4 v = xr[j * 64 + lane];
      ushort4 o;
      o.x = f2bf(v.x); o.y = f2bf(v.y); o.z = f2bf(v.z); o.w = f2bf(v.w);
      xw[j * 64 + lane] = o;
      int dbase = j * 256 + lane * 4;
#pragma unroll
      for (int e = 0; e < E_; ++e) {
        float4 w = *(const float4*)(lwr + e * D_ + dbase);
        acc[e] += (double)v.x * w.x + (double)v.y * w.y +
                  (double)v.z * w.z + (double)v.w * w.w;
      }
    }
#pragma unroll
    for (int e = 0; e < E_; ++e) {
      acc[e] += __shfl_xor(acc[e], 1, 64);
      acc[e] += __shfl_xor(acc[e], 2, 64);
      acc[e] += __shfl_xor(acc[e], 4, 64);
    }
    double s01 = (lane & 1) ? acc[1] : acc[0];
    double s23 = (lane & 1) ? acc[3] : acc[2];
    double s45 = (lane & 1) ? acc[5] : acc[4];
    double s67 = (lane & 1) ? acc[7] : acc[6];
    double t0 = (lane & 2) ? s23 : s01;
    double t1 = (lane & 2) ? s67 : s45;
    double u  = (lane & 4) ? t1 : t0;
    u += __shfl_xor(u, 8, 64);
    u += __shfl_xor(u, 16, 64);
    u += __shfl_xor(u, 32, 64);
    double lg[E_];
#pragma unroll
    for (int e = 0; e < E_; ++e) lg[e] = __shfl(u, e, 64);
    int e1 = 0; double b1 = lg[0];
#pragma unroll
    for (int e = 1; e < E_; ++e) if (lg[e] > b1) { b1 = lg[e]; e1 = e; }
    int e2 = (e1 == 0) ? 1 : 0; double b2 = lg[e2];
#pragma unroll
    for (int e = 0; e < E_; ++e) if (e != e1 && lg[e] > b2) { b2 = lg[e]; e2 = e; }
    if (lane == 0) {
      sel[2 * t]     = e1;
      sel[2 * t + 1] = e2;
    }
  }
}

// ---------------- 2. per-block expert histograms ----------------
__global__ __launch_bounds__(256) void k_blkcnt(const int* __restrict__ sel,
                                                int* __restrict__ blkCnt) {
  __shared__ int cnt[E_];
  if (threadIdx.x < E_) cnt[threadIdx.x] = 0;
  __syncthreads();
  atomicAdd(&cnt[sel[blockIdx.x * 256 + threadIdx.x]], 1);
  __syncthreads();
  if (threadIdx.x < E_) blkCnt[blockIdx.x * E_ + threadIdx.x] = cnt[threadIdx.x];
}

// ---------------- 3. tiny scans + 128-row tile table (1 block) ----------------
// tile word: bits0-14 rowBase | bits15-17 e | bit18 is128 | bits19-27 mValid
__global__ void k_scan(const int* __restrict__ blkCnt,
                       int* __restrict__ counts,
                       int* __restrict__ cum_p, int* __restrict__ totals,
                       int* __restrict__ blkOff, int* __restrict__ tiles) {
  int tid = threadIdx.x;
  if (tid < E_) {
    int run = 0;
    for (int b = 0; b < NBR_; ++b) {
      blkOff[b * E_ + tid] = run;
      run += blkCnt[b * E_ + tid];
    }
    counts[tid] = run;
  }
  __syncthreads();
  if (tid == 0) {
    int cp = 0, nt = 0;
    cum_p[0] = 0;
    for (int e = 0; e < E_; ++e) {
      int cnt = counts[e];
      int gs = (cnt + 63) / 64 * 64;
      int r = 0;
      while (r < gs) {
        int m = (gs - r >= 128) ? 128 : 64;
        int mv = cnt - r;
        if (mv < 0) mv = 0;
        if (mv > m) mv = m;
        tiles[nt++] = (cp + r) | (e << 15) | ((m == 128) ? (1 << 18) : 0) | (mv << 19);
        r += m;
      }
      cp += gs;
      cum_p[e + 1] = cp;
    }
    totals[0] = cp;
    totals[1] = nt;
  }
}

// ---------------- 4. stable rank -> row_src ----------------
__global__ __launch_bounds__(256) void k_rowsrc(const int* __restrict__ sel,
                                                const int* __restrict__ cum_p,
                                                const int* __restrict__ blkOff,
                                                int* __restrict__ row_src) {
  __shared__ int se[256];
  int i = blockIdx.x * 256 + threadIdx.x;
  int e = sel[i];
  se[threadIdx.x] = e;
  __syncthreads();
  int r = 0;
  for (int j = 0; j < threadIdx.x; ++j) r += (se[j] == e);
  row_src[cum_p[e] + blkOff[blockIdx.x * E_ + e] + r] = i >> 1;
}

// ---------------- 5. w1 [d][16384] f32 -> w1t [n][1024] bf16 ----------------
__global__ __launch_bounds__(256) void k_w1conv(const float* __restrict__ w1,
                                                unsigned short* __restrict__ w1t) {
  __shared__ unsigned short lds[64][258];
  int n0 = blockIdx.x * 256, d0 = blockIdx.y * 64;
  int tid = threadIdx.x;
  int rIn = tid >> 6, c4 = tid & 63;
#pragma unroll
  for (int p = 0; p < 16; ++p) {
    int row = p * 4 + rIn;
    float4 v = *(const float4*)(w1 + (size_t)(d0 + row) * 16384 + n0 + c4 * 4);
    lds[row][c4 * 4 + 0] = f2bf(v.x);
    lds[row][c4 * 4 + 1] = f2bf(v.y);
    lds[row][c4 * 4 + 2] = f2bf(v.z);
    lds[row][c4 * 4 + 3] = f2bf(v.w);
  }
  __syncthreads();
  int d2 = (tid & 15) * 4, nn = tid >> 4;
#pragma unroll
  for (int q = 0; q < 16; ++q) {
    int n = q * 16 + nn;
    ushort4 o;
    o.x = lds[d2 + 0][n]; o.y = lds[d2 + 1][n];
    o.z = lds[d2 + 2][n]; o.w = lds[d2 + 3][n];
    *(ushort4*)(w1t + (size_t)(n0 + n) * 1024 + d0 + d2) = o;
  }
}

// ---------------- 6. grouped GEMM: m97 structure (128x128, BK=64, single 32KiB buf) ----------------
// A staged DIRECTLY from gathered xbf rows via per-lane global_load_lds source (scatter fused).
// LDS rows swizzled: byte_in_row ^= (row&7)<<4 (inverse swizzle on global src, swizzle on read).
// 4-5 blocks/CU co-resident hide the per-tile vmcnt drain + barriers (m114 mechanism).

#define READ_A(dst, KS)                                                         \
  {                                                                             \
    const unsigned short* p_ = As + (wr * 64 + lane15) * 64;                    \
    int co_ = (((KS) * 64 + g16) ^ swz) >> 1;                                   \
    _Pragma("unroll") for (int mi = 0; mi < 4; ++mi)                            \
      dst[mi] = *(const bf16x8*)(p_ + mi * 1024 + co_);                         \
  }

#define READ_B(dst, KS)                                                         \
  {                                                                             \
    const unsigned short* p_ = Bs + (wc * 64 + lane15) * 64;                    \
    int co_ = (((KS) * 64 + g16) ^ swz) >> 1;                                   \
    _Pragma("unroll") for (int ni = 0; ni < 4; ++ni)                            \
      dst[ni] = *(const bf16x8*)(p_ + ni * 1024 + co_);                         \
  }

#define MFMA16(AV, BV)                                                          \
  __builtin_amdgcn_s_setprio(1);                                                \
  _Pragma("unroll") for (int mi = 0; mi < 4; ++mi)                              \
    _Pragma("unroll") for (int ni = 0; ni < 4; ++ni)                            \
      acc[mi][ni] = __builtin_amdgcn_mfma_f32_16x16x32_bf16(                    \
          AV[mi], BV[ni], acc[mi][ni], 0, 0, 0);                                \
  __builtin_amdgcn_s_setprio(0);

__global__ __launch_bounds__(256, 4) void k_gemm(const unsigned short* __restrict__ xbf,
                                                 const unsigned short* __restrict__ w1t,
                                                 const int* __restrict__ row_src,
                                                 const int* __restrict__ tiles,
                                                 const int* __restrict__ totals,
                                                 float* __restrict__ out) {
  // T1: bijective XCD chunking (2304 = 8*288); mtile-major inside a chunk so the
  // 16 ny-blocks sharing an A-panel land on one XCD back-to-back.
  int P = blockIdx.y * MAXT_ + blockIdx.x;
  int L = (P & 7) * (MAXT_ * 16 / 8) + (P >> 3);
  int mtile = L >> 4, ny = L & 15;
  if (mtile >= totals[1]) return;

  int info = tiles[mtile];
  int rowBase = info & 0x7FFF;
  int e = (info >> 15) & 7;
  int mLimit = ((info >> 18) & 1) ? 128 : 64;
  int mValid = (info >> 19) & 0x1FF;

  __shared__ unsigned short As[128 * 64];
  __shared__ unsigned short Bs[128 * 64];

  int tid = threadIdx.x, wave = tid >> 6, lane = tid & 63;
  int lane15 = lane & 15;
  int g16 = (lane >> 4) * 16;          // byte offset of k-group
  int swz = (lane15 & 7) << 4;         // read-side swizzle (bytes)
  int wr = wave >> 1, wc = wave & 1;

  // staging geometry: 8 lanes per row, 16B each; inverse-swizzled source column
  int rr = tid >> 3;                           // 0..31 row within 32-row region
  int co = ((tid & 7) ^ (rr & 7)) << 3;        // elem offset (inverse swizzle)
  int woff = (tid >> 6) << 9;                  // wave*512 elems LDS dst offset

  // gathered A sources (one per 32-row region), clamped for padding rows
  const unsigned short* Asrc[4];
#pragma unroll
  for (int q = 0; q < 4; ++q) {
    int sr = row_src[rowBase + q * 32 + rr];
    sr = (sr < 0) ? 0 : sr;                    // garbage rows masked at epilogue
    Asrc[q] = xbf + (size_t)sr * D_ + co;
  }
  const unsigned short* Bg = w1t + ((size_t)e * DFFN_ + (size_t)ny * 128) * D_;

  f32x4 acc[4][4];
#pragma unroll
  for (int i = 0; i < 4; ++i)
#pragma unroll
    for (int j = 0; j < 4; ++j) acc[i][j] = (f32x4){0.f, 0.f, 0.f, 0.f};

  for (int t = 0; t < 16; ++t) {
    int k0 = t * 64;
#pragma unroll
    for (int q = 0; q < 4; ++q)
      __builtin_amdgcn_global_load_lds(
          (const __attribute__((address_space(1))) void*)(Asrc[q] + k0),
          (__attribute__((address_space(3))) void*)(As + q * 2048 + woff), 16, 0, 0);
#pragma unroll
    for (int q = 0; q < 4; ++q)
      __builtin_amdgcn_global_load_lds(
          (const __attribute__((address_space(1))) void*)(Bg + (size_t)(q * 32 + rr) * D_ + k0 + co),
          (__attribute__((address_space(3))) void*)(Bs + q * 2048 + woff), 16, 0, 0);
    __syncthreads();   // drains vmcnt+lgkm then barrier (m97 structure)

    bf16x8 a0[4], b0[4], a1[4], b1[4];
    READ_A(a0, 0);
    READ_B(b0, 0);
    MFMA16(a0, b0);
    READ_A(a1, 1);
    READ_B(b1, 1);
    MFMA16(a1, b1);
    __syncthreads();   // all waves done reading before next tile overwrites
  }

  // epilogue: C layout col=lane&15, row=(lane>>4)*4+q; mask padding rows to 0
#pragma unroll
  for (int mi = 0; mi < 4; ++mi) {
    int mrow = wr * 64 + mi * 16;
    if (mrow >= mLimit) continue;
    int rbase = mrow + (lane >> 4) * 4;
#pragma unroll
    for (int ni = 0; ni < 4; ++ni) {
      int col = ny * 128 + wc * 64 + ni * 16 + lane15;
      f32x4 v = acc[mi][ni];
#pragma unroll
      for (int q = 0; q < 4; ++q) {
        float val = (rbase + q < mValid) ? v[q] : 0.0f;
        out[(size_t)(rowBase + rbase + q) * DFFN_ + col] = val;
      }
    }
  }
}

// ---------------- 7. zero tail rows >= total_padded ----------------
__global__ __launch_bounds__(256) void k_ztail(const int* __restrict__ totals,
                                               float* __restrict__ out) {
  int row = TK_ + blockIdx.x;          // 16384 .. 16895
  if (row < totals[0]) return;
  float4 z = {0.f, 0.f, 0.f, 0.f};
  float4* o = (float4*)(out + (size_t)row * DFFN_);
  o[threadIdx.x] = z;
  o[threadIdx.x + 256] = z;
}

extern "C" void kernel_launch(void* const* d_in, const int* in_sizes, int n_in,
                              void* d_out, int out_size, void* d_ws, size_t ws_size,
                              hipStream_t stream) {
  const float* x  = (const float*)d_in[0];
  const float* wr = (const float*)d_in[1];
  const float* w1 = (const float*)d_in[2];
  float* out = (float*)d_out;
  char* ws = (char*)d_ws;

  int* sel     = (int*)(ws + WS_SEL);
  int* counts  = (int*)(ws + WS_COUNTS);
  int* cum_p   = (int*)(ws + WS_CUMP);
  int* totals  = (int*)(ws + WS_TOTALS);
  int* blkCnt  = (int*)(ws + WS_BLKCNT);
  int* blkOff  = (int*)(ws + WS_BLKOFF);
  int* tiles   = (int*)(ws + WS_TILES);
  int* row_src = (int*)(ws + WS_ROWSRC);
  unsigned short* xbf = (unsigned short*)(ws + WS_XBF);
  unsigned short* w1t = (unsigned short*)(ws + WS_W1T);

  hipMemsetAsync(row_src, 0xFF, CAP_ * sizeof(int), stream);

  k_w1conv<<<dim3(64, 16), 256, 0, stream>>>(w1, w1t);
  k_router<<<T_ / 16, 256, 0, stream>>>(x, wr, sel, xbf);
  k_blkcnt<<<NBR_, 256, 0, stream>>>(sel, blkCnt);
  k_scan<<<1, 64, 0, stream>>>(blkCnt, counts, cum_p, totals, blkOff, tiles);
  k_rowsrc<<<NBR_, 256, 0, stream>>>(sel, cum_p, blkOff, row_src);
  k_gemm<<<dim3(MAXT_, 16), 256, 0, stream>>>(xbf, w1t, row_src, tiles, totals, out);
  k_ztail<<<512, 256, 0, stream>>>(totals, out);
}

// Round 8
// 160.541 us; speedup vs baseline: 1.2430x; 1.0386x over previous
//
#include <hip/hip_runtime.h>
#include <stdint.h>

#define E_       8
#define D_       1024
#define DFFN_    2048
#define T_       8192
#define TK_      16384
#define CAP_     16896
#define NBR_     64        // TK_/256 rank blocks
#define MAXT_    144       // max 128-row tiles

// workspace layout (bytes)
#define WS_SEL      0u          // TK_*4
#define WS_COUNTS   0x10000u    // 8*4
#define WS_CUMP     0x10100u    // 9*4
#define WS_TOTALS   0x10200u    // [0]=total_padded [1]=nTiles
#define WS_BLKCNT   0x10300u    // NBR_*8*4
#define WS_BLKOFF   0x10B00u    // NBR_*8*4
#define WS_TILES    0x11300u    // MAXT_*4
#define WS_ROWSRC   0x12000u    // CAP_*4
#define WS_XBF      0x23000u    // T_*1024*2 = 16777216
#define WS_W1T      (0x23000u + 34603008u)  // 16384*1024*2

typedef __bf16 bf16x8 __attribute__((ext_vector_type(8)));
typedef float  f32x4  __attribute__((ext_vector_type(4)));

__device__ __forceinline__ unsigned short f2bf(float f) {
  union { float f; uint32_t u; } v; v.f = f;
  return (unsigned short)((v.u + 0x7fffu + ((v.u >> 16) & 1u)) >> 16);
}

// ---------------- 1. fused router (blocks 0..511) + w1conv (blocks 512..1535) ----------------
__global__ __launch_bounds__(256) void k_rw(const float* __restrict__ x,
                                            const float* __restrict__ wr,
                                            const float* __restrict__ w1,
                                            int* __restrict__ sel,
                                            unsigned short* __restrict__ xbf,
                                            unsigned short* __restrict__ w1t) {
  __shared__ __align__(16) unsigned char smem[66560];  // max(router 32KB, w1conv 33KB)
  int tid = threadIdx.x;

  if ((int)blockIdx.x < 512) {
    // ---------- router: top-2 expert ids + bf16 cast of x ----------
    float* lwr = (float*)smem;
    for (int i = tid; i < E_ * D_ / 4; i += 256)
      ((float4*)lwr)[i] = ((const float4*)wr)[i];
    __syncthreads();
    int wave = tid >> 6, lane = tid & 63;

    for (int tk = 0; tk < 4; ++tk) {
      int t = blockIdx.x * 16 + wave * 4 + tk;
      double acc[E_];
#pragma unroll
      for (int e = 0; e < E_; ++e) acc[e] = 0.0;
      const float4* xr = (const float4*)(x + (size_t)t * D_);
      ushort4* xw = (ushort4*)(xbf + (size_t)t * D_);
#pragma unroll
      for (int j = 0; j < 4; ++j) {
        float4 v = xr[j * 64 + lane];
        ushort4 o;
        o.x = f2bf(v.x); o.y = f2bf(v.y); o.z = f2bf(v.z); o.w = f2bf(v.w);
        xw[j * 64 + lane] = o;
        int dbase = j * 256 + lane * 4;
#pragma unroll
        for (int e = 0; e < E_; ++e) {
          float4 w = *(const float4*)(lwr + e * D_ + dbase);
          acc[e] += (double)v.x * w.x + (double)v.y * w.y +
                    (double)v.z * w.z + (double)v.w * w.w;
        }
      }
#pragma unroll
      for (int e = 0; e < E_; ++e) {
        acc[e] += __shfl_xor(acc[e], 1, 64);
        acc[e] += __shfl_xor(acc[e], 2, 64);
        acc[e] += __shfl_xor(acc[e], 4, 64);
      }
      double s01 = (lane & 1) ? acc[1] : acc[0];
      double s23 = (lane & 1) ? acc[3] : acc[2];
      double s45 = (lane & 1) ? acc[5] : acc[4];
      double s67 = (lane & 1) ? acc[7] : acc[6];
      double t0 = (lane & 2) ? s23 : s01;
      double t1 = (lane & 2) ? s67 : s45;
      double u  = (lane & 4) ? t1 : t0;
      u += __shfl_xor(u, 8, 64);
      u += __shfl_xor(u, 16, 64);
      u += __shfl_xor(u, 32, 64);
      double lg[E_];
#pragma unroll
      for (int e = 0; e < E_; ++e) lg[e] = __shfl(u, e, 64);
      int e1 = 0; double b1 = lg[0];
#pragma unroll
      for (int e = 1; e < E_; ++e) if (lg[e] > b1) { b1 = lg[e]; e1 = e; }
      int e2 = (e1 == 0) ? 1 : 0; double b2 = lg[e2];
#pragma unroll
      for (int e = 0; e < E_; ++e) if (e != e1 && lg[e] > b2) { b2 = lg[e]; e2 = e; }
      if (lane == 0) {
        sel[2 * t]     = e1;
        sel[2 * t + 1] = e2;
      }
    }
  } else {
    // ---------- w1conv: w1 [d][16384] f32 -> w1t [n][1024] bf16 ----------
    typedef unsigned short row258[258];
    row258* lds = (row258*)smem;
    int bx = blockIdx.x - 512;
    int n0 = (bx & 63) * 256, d0 = (bx >> 6) * 64;
    int rIn = tid >> 6, c4 = tid & 63;
#pragma unroll
    for (int p = 0; p < 16; ++p) {
      int row = p * 4 + rIn;
      float4 v = *(const float4*)(w1 + (size_t)(d0 + row) * 16384 + n0 + c4 * 4);
      lds[row][c4 * 4 + 0] = f2bf(v.x);
      lds[row][c4 * 4 + 1] = f2bf(v.y);
      lds[row][c4 * 4 + 2] = f2bf(v.z);
      lds[row][c4 * 4 + 3] = f2bf(v.w);
    }
    __syncthreads();
    int d2 = (tid & 15) * 4, nn = tid >> 4;
#pragma unroll
    for (int q = 0; q < 16; ++q) {
      int n = q * 16 + nn;
      ushort4 o;
      o.x = lds[d2 + 0][n]; o.y = lds[d2 + 1][n];
      o.z = lds[d2 + 2][n]; o.w = lds[d2 + 3][n];
      *(ushort4*)(w1t + (size_t)(n0 + n) * 1024 + d0 + d2) = o;
    }
  }
}

// ---------------- 2. per-block expert histograms ----------------
__global__ __launch_bounds__(256) void k_blkcnt(const int* __restrict__ sel,
                                                int* __restrict__ blkCnt) {
  __shared__ int cnt[E_];
  if (threadIdx.x < E_) cnt[threadIdx.x] = 0;
  __syncthreads();
  atomicAdd(&cnt[sel[blockIdx.x * 256 + threadIdx.x]], 1);
  __syncthreads();
  if (threadIdx.x < E_) blkCnt[blockIdx.x * E_ + threadIdx.x] = cnt[threadIdx.x];
}

// ---------------- 3. tiny scans + 128-row tile table + row_src padding (1 block) ----------------
// tile word: bits0-14 rowBase | bits15-17 e | bit18 is128 | bits19-27 mValid
__global__ void k_scan(const int* __restrict__ blkCnt,
                       int* __restrict__ counts,
                       int* __restrict__ cum_p, int* __restrict__ totals,
                       int* __restrict__ blkOff, int* __restrict__ tiles,
                       int* __restrict__ row_src) {
  int tid = threadIdx.x;
  if (tid < E_) {
    int run = 0;
    for (int b = 0; b < NBR_; ++b) {
      blkOff[b * E_ + tid] = run;
      run += blkCnt[b * E_ + tid];
    }
    counts[tid] = run;
  }
  __syncthreads();
  if (tid == 0) {
    int cp = 0, nt = 0;
    cum_p[0] = 0;
    for (int e = 0; e < E_; ++e) {
      int cnt = counts[e];
      int gs = (cnt + 63) / 64 * 64;
      int r = 0;
      while (r < gs) {
        int m = (gs - r >= 128) ? 128 : 64;
        int mv = cnt - r;
        if (mv < 0) mv = 0;
        if (mv > m) mv = m;
        tiles[nt++] = (cp + r) | (e << 15) | ((m == 128) ? (1 << 18) : 0) | (mv << 19);
        r += m;
      }
      for (int i = cnt; i < gs; ++i) row_src[cp + i] = -1;  // padding rows (replaces memset)
      cp += gs;
      cum_p[e + 1] = cp;
    }
    totals[0] = cp;
    totals[1] = nt;
  }
}

// ---------------- 4. stable rank -> row_src ----------------
__global__ __launch_bounds__(256) void k_rowsrc(const int* __restrict__ sel,
                                                const int* __restrict__ cum_p,
                                                const int* __restrict__ blkOff,
                                                int* __restrict__ row_src) {
  __shared__ int se[256];
  int i = blockIdx.x * 256 + threadIdx.x;
  int e = sel[i];
  se[threadIdx.x] = e;
  __syncthreads();
  int r = 0;
  for (int j = 0; j < threadIdx.x; ++j) r += (se[j] == e);
  row_src[cum_p[e] + blkOff[blockIdx.x * E_ + e] + r] = i >> 1;
}

// ---------------- 5. grouped GEMM: 128x128 block, 2 waves, wave tile 64x128 ----------------
// m97 single-buffer sync (2 __syncthreads / K-tile), 32 KiB LDS -> 4 blocks/CU.
// Wave tile 64x128 cuts LDS-read/FLOP from 31.25 to 22.9 KB/MFLOP (LDS is the binding pipe).
// A staged via gathered per-lane global_load_lds source (scatter fused). Swizzle pair proven R3-R7.

#define READ_A(dst, KS)                                                         \
  {                                                                             \
    const unsigned short* p_ = As + (wr * 64 + lane15) * 64;                    \
    int co_ = (((KS) * 64 + g16) ^ swz) >> 1;                                   \
    _Pragma("unroll") for (int mi = 0; mi < 4; ++mi)                            \
      dst[mi] = *(const bf16x8*)(p_ + mi * 1024 + co_);                         \
  }

#define READ_B(dst, KS)                                                         \
  {                                                                             \
    const unsigned short* p_ = Bs + lane15 * 64;                                \
    int co_ = (((KS) * 64 + g16) ^ swz) >> 1;                                   \
    _Pragma("unroll") for (int ni = 0; ni < 8; ++ni)                            \
      dst[ni] = *(const bf16x8*)(p_ + ni * 1024 + co_);                         \
  }

#define MFMA32(AV, BV)                                                          \
  __builtin_amdgcn_s_setprio(1);                                                \
  _Pragma("unroll") for (int mi = 0; mi < 4; ++mi)                              \
    _Pragma("unroll") for (int ni = 0; ni < 8; ++ni)                            \
      acc[mi][ni] = __builtin_amdgcn_mfma_f32_16x16x32_bf16(                    \
          AV[mi], BV[ni], acc[mi][ni], 0, 0, 0);                                \
  __builtin_amdgcn_s_setprio(0);

__global__ __launch_bounds__(128, 2) void k_gemm(const unsigned short* __restrict__ xbf,
                                                 const unsigned short* __restrict__ w1t,
                                                 const int* __restrict__ row_src,
                                                 const int* __restrict__ tiles,
                                                 const int* __restrict__ totals,
                                                 float* __restrict__ out) {
  // T1: bijective XCD chunking (2304 = 8*288); mtile-major inside a chunk.
  int P = blockIdx.y * MAXT_ + blockIdx.x;
  int L = (P & 7) * (MAXT_ * 16 / 8) + (P >> 3);
  int mtile = L >> 4, ny = L & 15;
  if (mtile >= totals[1]) return;

  int info = tiles[mtile];
  int rowBase = info & 0x7FFF;
  int e = (info >> 15) & 7;
  int mLimit = ((info >> 18) & 1) ? 128 : 64;
  int mValid = (info >> 19) & 0x1FF;

  __shared__ unsigned short As[128 * 64];
  __shared__ unsigned short Bs[128 * 64];

  int tid = threadIdx.x, wave = tid >> 6, lane = tid & 63;
  int lane15 = lane & 15;
  int g16 = (lane >> 4) * 16;          // byte offset of k-group
  int swz = (lane15 & 7) << 4;         // read-side swizzle (bytes)
  int wr = wave;                       // 2 waves: wr in {0,1}

  // staging geometry: 8 lanes/row, 16B each; 128 threads cover 16 rows per call
  int rr = tid >> 3;                           // 0..15 row within 16-row region
  int co = ((tid & 7) ^ (rr & 7)) << 3;        // elem offset (inverse swizzle)
  int woff = wave << 9;                        // wave*512 elems LDS dst offset

  // gathered A source offsets (one per 16-row region), clamped for padding rows
  uint32_t aoff[8];
#pragma unroll
  for (int q = 0; q < 8; ++q) {
    int sr = row_src[rowBase + q * 16 + rr];
    sr = (sr < 0) ? 0 : sr;                    // garbage rows masked at epilogue
    aoff[q] = (uint32_t)sr * D_ + co;
  }
  const unsigned short* Bg = w1t + ((size_t)e * DFFN_ + (size_t)ny * 128) * D_ + co;

  f32x4 acc[4][8];
#pragma unroll
  for (int i = 0; i < 4; ++i)
#pragma unroll
    for (int j = 0; j < 8; ++j) acc[i][j] = (f32x4){0.f, 0.f, 0.f, 0.f};

  for (int t = 0; t < 16; ++t) {
    int k0 = t * 64;
#pragma unroll
    for (int q = 0; q < 8; ++q)
      __builtin_amdgcn_global_load_lds(
          (const __attribute__((address_space(1))) void*)(xbf + aoff[q] + k0),
          (__attribute__((address_space(3))) void*)(As + q * 1024 + woff), 16, 0, 0);
#pragma unroll
    for (int q = 0; q < 8; ++q)
      __builtin_amdgcn_global_load_lds(
          (const __attribute__((address_space(1))) void*)(Bg + (size_t)(q * 16 + rr) * D_ + k0),
          (__attribute__((address_space(3))) void*)(Bs + q * 1024 + woff), 16, 0, 0);
    __syncthreads();   // drains vmcnt+lgkm then barrier (m97 structure)

    bf16x8 a0[4], b0[8], a1[4], b1[8];
    READ_A(a0, 0);
    READ_B(b0, 0);
    MFMA32(a0, b0);
    READ_A(a1, 1);
    READ_B(b1, 1);
    MFMA32(a1, b1);
    __syncthreads();   // all waves done reading before next tile overwrites
  }

  // epilogue: C layout col=lane&15, row=(lane>>4)*4+q; mask padding rows to 0
#pragma unroll
  for (int mi = 0; mi < 4; ++mi) {
    int mrow = wr * 64 + mi * 16;
    if (mrow >= mLimit) continue;
    int rbase = mrow + (lane >> 4) * 4;
#pragma unroll
    for (int ni = 0; ni < 8; ++ni) {
      int col = ny * 128 + ni * 16 + lane15;
      f32x4 v = acc[mi][ni];
#pragma unroll
      for (int q = 0; q < 4; ++q) {
        float val = (rbase + q < mValid) ? v[q] : 0.0f;
        out[(size_t)(rowBase + rbase + q) * DFFN_ + col] = val;
      }
    }
  }
}

// ---------------- 6. zero tail rows >= total_padded ----------------
__global__ __launch_bounds__(256) void k_ztail(const int* __restrict__ totals,
                                               float* __restrict__ out) {
  int row = TK_ + blockIdx.x;          // 16384 .. 16895
  if (row < totals[0]) return;
  float4 z = {0.f, 0.f, 0.f, 0.f};
  float4* o = (float4*)(out + (size_t)row * DFFN_);
  o[threadIdx.x] = z;
  o[threadIdx.x + 256] = z;
}

extern "C" void kernel_launch(void* const* d_in, const int* in_sizes, int n_in,
                              void* d_out, int out_size, void* d_ws, size_t ws_size,
                              hipStream_t stream) {
  const float* x  = (const float*)d_in[0];
  const float* wr = (const float*)d_in[1];
  const float* w1 = (const float*)d_in[2];
  float* out = (float*)d_out;
  char* ws = (char*)d_ws;

  int* sel     = (int*)(ws + WS_SEL);
  int* counts  = (int*)(ws + WS_COUNTS);
  int* cum_p   = (int*)(ws + WS_CUMP);
  int* totals  = (int*)(ws + WS_TOTALS);
  int* blkCnt  = (int*)(ws + WS_BLKCNT);
  int* blkOff  = (int*)(ws + WS_BLKOFF);
  int* tiles   = (int*)(ws + WS_TILES);
  int* row_src = (int*)(ws + WS_ROWSRC);
  unsigned short* xbf = (unsigned short*)(ws + WS_XBF);
  unsigned short* w1t = (unsigned short*)(ws + WS_W1T);

  k_rw<<<1536, 256, 0, stream>>>(x, wr, w1, sel, xbf, w1t);
  k_blkcnt<<<NBR_, 256, 0, stream>>>(sel, blkCnt);
  k_scan<<<1, 64, 0, stream>>>(blkCnt, counts, cum_p, totals, blkOff, tiles, row_src);
  k_rowsrc<<<NBR_, 256, 0, stream>>>(sel, cum_p, blkOff, row_src);
  k_gemm<<<dim3(MAXT_, 16), 128, 0, stream>>>(xbf, w1t, row_src, tiles, totals, out);
  k_ztail<<<512, 256, 0, stream>>>(totals, out);
}

// Round 9
// 157.369 us; speedup vs baseline: 1.2681x; 1.0202x over previous
//
#include <hip/hip_runtime.h>
#include <stdint.h>

#define E_       8
#define D_       1024
#define DFFN_    2048
#define T_       8192
#define TK_      16384
#define CAP_     16896
#define MAXT_    144       // max 128-row tiles

// workspace layout (bytes)
#define WS_SEL      0u          // TK_*4
#define WS_TOTALS   0x10200u    // [0]=total_padded [1]=nTiles
#define WS_TILES    0x11300u    // MAXT_*4
#define WS_ROWSRC   0x12000u    // (CAP_+64)*4  (fits before WS_XBF)
#define WS_XBF      0x23000u    // T_*1024*2 = 16777216
#define WS_W1T      (0x23000u + 34603008u)  // 16384*1024*2

typedef __bf16 bf16x8 __attribute__((ext_vector_type(8)));
typedef float  f32x4  __attribute__((ext_vector_type(4)));

__device__ __forceinline__ unsigned short f2bf(float f) {
  union { float f; uint32_t u; } v; v.f = f;
  return (unsigned short)((v.u + 0x7fffu + ((v.u >> 16) & 1u)) >> 16);
}

// ---------------- 1. fused router (blocks 0..511) + w1conv (blocks 512..1535) ----------------
__global__ __launch_bounds__(256) void k_rw(const float* __restrict__ x,
                                            const float* __restrict__ wr,
                                            const float* __restrict__ w1,
                                            int* __restrict__ sel,
                                            unsigned short* __restrict__ xbf,
                                            unsigned short* __restrict__ w1t) {
  __shared__ __align__(16) unsigned char smem[66560];
  int tid = threadIdx.x;

  if ((int)blockIdx.x < 512) {
    // ---------- router: top-2 expert ids + bf16 cast of x ----------
    float* lwr = (float*)smem;
    for (int i = tid; i < E_ * D_ / 4; i += 256)
      ((float4*)lwr)[i] = ((const float4*)wr)[i];
    __syncthreads();
    int wave = tid >> 6, lane = tid & 63;

    for (int tk = 0; tk < 4; ++tk) {
      int t = blockIdx.x * 16 + wave * 4 + tk;
      double acc[E_];
#pragma unroll
      for (int e = 0; e < E_; ++e) acc[e] = 0.0;
      const float4* xr = (const float4*)(x + (size_t)t * D_);
      ushort4* xw = (ushort4*)(xbf + (size_t)t * D_);
#pragma unroll
      for (int j = 0; j < 4; ++j) {
        float4 v = xr[j * 64 + lane];
        ushort4 o;
        o.x = f2bf(v.x); o.y = f2bf(v.y); o.z = f2bf(v.z); o.w = f2bf(v.w);
        xw[j * 64 + lane] = o;
        int dbase = j * 256 + lane * 4;
#pragma unroll
        for (int e = 0; e < E_; ++e) {
          float4 w = *(const float4*)(lwr + e * D_ + dbase);
          acc[e] += (double)v.x * w.x + (double)v.y * w.y +
                    (double)v.z * w.z + (double)v.w * w.w;
        }
      }
#pragma unroll
      for (int e = 0; e < E_; ++e) {
        acc[e] += __shfl_xor(acc[e], 1, 64);
        acc[e] += __shfl_xor(acc[e], 2, 64);
        acc[e] += __shfl_xor(acc[e], 4, 64);
      }
      double s01 = (lane & 1) ? acc[1] : acc[0];
      double s23 = (lane & 1) ? acc[3] : acc[2];
      double s45 = (lane & 1) ? acc[5] : acc[4];
      double s67 = (lane & 1) ? acc[7] : acc[6];
      double t0 = (lane & 2) ? s23 : s01;
      double t1 = (lane & 2) ? s67 : s45;
      double u  = (lane & 4) ? t1 : t0;
      u += __shfl_xor(u, 8, 64);
      u += __shfl_xor(u, 16, 64);
      u += __shfl_xor(u, 32, 64);
      double lg[E_];
#pragma unroll
      for (int e = 0; e < E_; ++e) lg[e] = __shfl(u, e, 64);
      int e1 = 0; double b1 = lg[0];
#pragma unroll
      for (int e = 1; e < E_; ++e) if (lg[e] > b1) { b1 = lg[e]; e1 = e; }
      int e2 = (e1 == 0) ? 1 : 0; double b2 = lg[e2];
#pragma unroll
      for (int e = 0; e < E_; ++e) if (e != e1 && lg[e] > b2) { b2 = lg[e]; e2 = e; }
      if (lane == 0) {
        sel[2 * t]     = e1;
        sel[2 * t + 1] = e2;
      }
    }
  } else {
    // ---------- w1conv: w1 [d][16384] f32 -> w1t [n][1024] bf16 ----------
    typedef unsigned short row258[258];
    row258* lds = (row258*)smem;
    int bx = blockIdx.x - 512;
    int n0 = (bx & 63) * 256, d0 = (bx >> 6) * 64;
    int rIn = tid >> 6, c4 = tid & 63;
#pragma unroll
    for (int p = 0; p < 16; ++p) {
      int row = p * 4 + rIn;
      float4 v = *(const float4*)(w1 + (size_t)(d0 + row) * 16384 + n0 + c4 * 4);
      lds[row][c4 * 4 + 0] = f2bf(v.x);
      lds[row][c4 * 4 + 1] = f2bf(v.y);
      lds[row][c4 * 4 + 2] = f2bf(v.z);
      lds[row][c4 * 4 + 3] = f2bf(v.w);
    }
    __syncthreads();
    int d2 = (tid & 15) * 4, nn = tid >> 4;
#pragma unroll
    for (int q = 0; q < 16; ++q) {
      int n = q * 16 + nn;
      ushort4 o;
      o.x = lds[d2 + 0][n]; o.y = lds[d2 + 1][n];
      o.z = lds[d2 + 2][n]; o.w = lds[d2 + 3][n];
      *(ushort4*)(w1t + (size_t)(n0 + n) * 1024 + d0 + d2) = o;
    }
  }
}

// ---------------- 2. full counting-sort in ONE block (1024 threads) ----------------
// Replaces blkcnt+scan+rowsrc. Thread t owns sel[16t..16t+15] (span). Stable rank =
// expert-base + chunk-base + span-base + local. All runtime-indexed counters in LDS.
// tile word: bits0-14 rowBase | bits15-17 e | bit18 is128 | bits19-27 mValid
__global__ __launch_bounds__(1024) void k_sort(const int* __restrict__ sel,
                                               int* __restrict__ totals,
                                               int* __restrict__ tiles,
                                               int* __restrict__ row_src) {
  __shared__ int spanCnt[1024][9];   // [t][e] span histogram / phase-3 running counter
  __shared__ int spanOff[1024][9];   // [t][e] prefix of spans within chunk
  __shared__ int chunkOff[64][8];    // [c][e] prefix of chunks within expert
  __shared__ int scnt[8];            // tokens per expert
  __shared__ int scum[9];            // padded cumulative (cum_p)
  __shared__ int lsel[16384];
  int t = threadIdx.x;
  int base = t * 16;

  // phase 1: load + span histogram
#pragma unroll
  for (int e = 0; e < 8; ++e) spanCnt[t][e] = 0;
#pragma unroll
  for (int j = 0; j < 16; ++j) {
    int e = sel[base + j];
    lsel[base + j] = e;
    spanCnt[t][e] += 1;
  }
  __syncthreads();

  // phase 2a: prefix over 16 spans per (chunk, expert); chunk total -> chunkOff
  if (t < 512) {
    int c = t >> 3, e = t & 7;
    int run = 0;
#pragma unroll
    for (int s = 0; s < 16; ++s) {
      spanOff[c * 16 + s][e] = run;
      run += spanCnt[c * 16 + s][e];
    }
    chunkOff[c][e] = run;  // temporarily chunk count
  }
  __syncthreads();

  // phase 2b: prefix over 64 chunks per expert
  if (t < 8) {
    int run = 0;
    for (int c = 0; c < 64; ++c) {
      int v = chunkOff[c][t];
      chunkOff[c][t] = run;
      run += v;
    }
    scnt[t] = run;
  }
  __syncthreads();

  // phase 2c: cum_p, tile table, totals
  if (t == 0) {
    int cp = 0, nt = 0;
    scum[0] = 0;
    for (int e = 0; e < E_; ++e) {
      int cnt = scnt[e];
      int gs = (cnt + 63) / 64 * 64;
      int r = 0;
      while (r < gs) {
        int m = (gs - r >= 128) ? 128 : 64;
        int mv = cnt - r;
        if (mv < 0) mv = 0;
        if (mv > m) mv = m;
        tiles[nt++] = (cp + r) | (e << 15) | ((m == 128) ? (1 << 18) : 0) | (mv << 19);
        r += m;
      }
      cp += gs;
      scum[e + 1] = cp;
    }
    totals[0] = cp;
    totals[1] = nt;
  }
  __syncthreads();

  // phase 2d: padding rows -> -1 (per-expert pad regions + everything past totals[0])
  for (int e = 0; e < E_; ++e) {
    int s = scum[e] + scnt[e], en = scum[e + 1];
    for (int i = s + t; i < en; i += 1024) row_src[i] = -1;
  }
  for (int i = scum[8] + t; i < CAP_ + 64; i += 1024) row_src[i] = -1;

  // phase 3: stable ranks (reuse spanCnt as running local counter)
#pragma unroll
  for (int e = 0; e < 8; ++e) spanCnt[t][e] = 0;
#pragma unroll
  for (int j = 0; j < 16; ++j) {
    int e = lsel[base + j];
    int dst = scum[e] + chunkOff[t >> 4][e] + spanOff[t][e] + spanCnt[t][e];
    spanCnt[t][e] += 1;
    row_src[dst] = (base + j) >> 1;
  }
}

// ---------------- 3. grouped GEMM: m97 structure (R7 exact: 128x128, BK=64, 32KiB, 4 waves) ----------------
#define READ_A(dst, KS)                                                         \
  {                                                                             \
    const unsigned short* p_ = As + (wr * 64 + lane15) * 64;                    \
    int co_ = (((KS) * 64 + g16) ^ swz) >> 1;                                   \
    _Pragma("unroll") for (int mi = 0; mi < 4; ++mi)                            \
      dst[mi] = *(const bf16x8*)(p_ + mi * 1024 + co_);                         \
  }

#define READ_B(dst, KS)                                                         \
  {                                                                             \
    const unsigned short* p_ = Bs + (wc * 64 + lane15) * 64;                    \
    int co_ = (((KS) * 64 + g16) ^ swz) >> 1;                                   \
    _Pragma("unroll") for (int ni = 0; ni < 4; ++ni)                            \
      dst[ni] = *(const bf16x8*)(p_ + ni * 1024 + co_);                         \
  }

#define MFMA16(AV, BV)                                                          \
  __builtin_amdgcn_s_setprio(1);                                                \
  _Pragma("unroll") for (int mi = 0; mi < 4; ++mi)                              \
    _Pragma("unroll") for (int ni = 0; ni < 4; ++ni)                            \
      acc[mi][ni] = __builtin_amdgcn_mfma_f32_16x16x32_bf16(                    \
          AV[mi], BV[ni], acc[mi][ni], 0, 0, 0);                                \
  __builtin_amdgcn_s_setprio(0);

__global__ __launch_bounds__(256, 4) void k_gemm(const unsigned short* __restrict__ xbf,
                                                 const unsigned short* __restrict__ w1t,
                                                 const int* __restrict__ row_src,
                                                 const int* __restrict__ tiles,
                                                 const int* __restrict__ totals,
                                                 float* __restrict__ out) {
  // T1: bijective XCD chunking; mtile-major inside a chunk.
  int P = blockIdx.y * MAXT_ + blockIdx.x;
  int L = (P & 7) * (MAXT_ * 16 / 8) + (P >> 3);
  int mtile = L >> 4, ny = L & 15;
  if (mtile >= totals[1]) return;

  int info = tiles[mtile];
  int rowBase = info & 0x7FFF;
  int e = (info >> 15) & 7;
  int mLimit = ((info >> 18) & 1) ? 128 : 64;
  int mValid = (info >> 19) & 0x1FF;

  __shared__ unsigned short As[128 * 64];
  __shared__ unsigned short Bs[128 * 64];

  int tid = threadIdx.x, wave = tid >> 6, lane = tid & 63;
  int lane15 = lane & 15;
  int g16 = (lane >> 4) * 16;          // byte offset of k-group
  int swz = (lane15 & 7) << 4;         // read-side swizzle (bytes)
  int wr = wave >> 1, wc = wave & 1;

  // staging geometry: 8 lanes/row, 16B each; inverse-swizzled source column
  int rr = tid >> 3;                           // 0..31 row within 32-row region
  int co = ((tid & 7) ^ (rr & 7)) << 3;        // elem offset (inverse swizzle)
  int woff = (tid >> 6) << 9;                  // wave*512 elems LDS dst offset

  // gathered A sources (one per 32-row region), clamped both ways
  const unsigned short* Asrc[4];
#pragma unroll
  for (int q = 0; q < 4; ++q) {
    int sr = row_src[rowBase + q * 32 + rr];
    if ((unsigned)sr >= (unsigned)T_) sr = 0;  // padding/garbage rows masked at epilogue
    Asrc[q] = xbf + (size_t)sr * D_ + co;
  }
  const unsigned short* Bg = w1t + ((size_t)e * DFFN_ + (size_t)ny * 128) * D_;

  f32x4 acc[4][4];
#pragma unroll
  for (int i = 0; i < 4; ++i)
#pragma unroll
    for (int j = 0; j < 4; ++j) acc[i][j] = (f32x4){0.f, 0.f, 0.f, 0.f};

  for (int t = 0; t < 16; ++t) {
    int k0 = t * 64;
#pragma unroll
    for (int q = 0; q < 4; ++q)
      __builtin_amdgcn_global_load_lds(
          (const __attribute__((address_space(1))) void*)(Asrc[q] + k0),
          (__attribute__((address_space(3))) void*)(As + q * 2048 + woff), 16, 0, 0);
#pragma unroll
    for (int q = 0; q < 4; ++q)
      __builtin_amdgcn_global_load_lds(
          (const __attribute__((address_space(1))) void*)(Bg + (size_t)(q * 32 + rr) * D_ + k0 + co),
          (__attribute__((address_space(3))) void*)(Bs + q * 2048 + woff), 16, 0, 0);
    __syncthreads();   // drains vmcnt+lgkm then barrier (m97 structure)

    bf16x8 a0[4], b0[4], a1[4], b1[4];
    READ_A(a0, 0);
    READ_B(b0, 0);
    MFMA16(a0, b0);
    READ_A(a1, 1);
    READ_B(b1, 1);
    MFMA16(a1, b1);
    __syncthreads();   // all waves done reading before next tile overwrites
  }

  // epilogue: C layout col=lane&15, row=(lane>>4)*4+q; mask padding rows to 0
#pragma unroll
  for (int mi = 0; mi < 4; ++mi) {
    int mrow = wr * 64 + mi * 16;
    if (mrow >= mLimit) continue;
    int rbase = mrow + (lane >> 4) * 4;
#pragma unroll
    for (int ni = 0; ni < 4; ++ni) {
      int col = ny * 128 + wc * 64 + ni * 16 + lane15;
      f32x4 v = acc[mi][ni];
#pragma unroll
      for (int q = 0; q < 4; ++q) {
        float val = (rbase + q < mValid) ? v[q] : 0.0f;
        out[(size_t)(rowBase + rbase + q) * DFFN_ + col] = val;
      }
    }
  }
}

// ---------------- 4. zero tail rows >= total_padded ----------------
__global__ __launch_bounds__(256) void k_ztail(const int* __restrict__ totals,
                                               float* __restrict__ out) {
  int row = TK_ + blockIdx.x;          // 16384 .. 16895
  if (row < totals[0]) return;
  float4 z = {0.f, 0.f, 0.f, 0.f};
  float4* o = (float4*)(out + (size_t)row * DFFN_);
  o[threadIdx.x] = z;
  o[threadIdx.x + 256] = z;
}

extern "C" void kernel_launch(void* const* d_in, const int* in_sizes, int n_in,
                              void* d_out, int out_size, void* d_ws, size_t ws_size,
                              hipStream_t stream) {
  const float* x  = (const float*)d_in[0];
  const float* wr = (const float*)d_in[1];
  const float* w1 = (const float*)d_in[2];
  float* out = (float*)d_out;
  char* ws = (char*)d_ws;

  int* sel     = (int*)(ws + WS_SEL);
  int* totals  = (int*)(ws + WS_TOTALS);
  int* tiles   = (int*)(ws + WS_TILES);
  int* row_src = (int*)(ws + WS_ROWSRC);
  unsigned short* xbf = (unsigned short*)(ws + WS_XBF);
  unsigned short* w1t = (unsigned short*)(ws + WS_W1T);

  k_rw<<<1536, 256, 0, stream>>>(x, wr, w1, sel, xbf, w1t);
  k_sort<<<1, 1024, 0, stream>>>(sel, totals, tiles, row_src);
  k_ztail<<<512, 256, 0, stream>>>(totals, out);
  k_gemm<<<dim3(MAXT_, 16), 256, 0, stream>>>(xbf, w1t, row_src, tiles, totals, out);
}

// Round 10
// 156.827 us; speedup vs baseline: 1.2725x; 1.0035x over previous
//
#include <hip/hip_runtime.h>
#include <stdint.h>

#define E_       8
#define D_       1024
#define DFFN_    2048
#define T_       8192
#define TK_      16384
#define CAP_     16896
#define MAXT_    144       // max 128-row tiles

// workspace layout (bytes)
#define WS_SEL      0u          // TK_*4
#define WS_TOTALS   0x10200u    // [0]=total_padded [1]=nTiles
#define WS_TILES    0x11300u    // MAXT_*4
#define WS_ROWSRC   0x12000u    // (CAP_+64)*4  (fits before WS_XBF)
#define WS_XBF      0x23000u    // T_*1024*2 = 16777216
#define WS_W1T      (0x23000u + 34603008u)  // 16384*1024*2

typedef __bf16 bf16x8 __attribute__((ext_vector_type(8)));
typedef float  f32x4  __attribute__((ext_vector_type(4)));

__device__ __forceinline__ unsigned short f2bf(float f) {
  union { float f; uint32_t u; } v; v.f = f;
  return (unsigned short)((v.u + 0x7fffu + ((v.u >> 16) & 1u)) >> 16);
}

// ---- 1. fused: router (0..511) + w1conv (512..1535) + out-tail zero (1536..2047) ----
// smem sized to MAX branch need (33024 B), NOT the sum: 4 blocks/CU co-residency.
__global__ __launch_bounds__(256) void k_rw(const float* __restrict__ x,
                                            const float* __restrict__ wr,
                                            const float* __restrict__ w1,
                                            int* __restrict__ sel,
                                            unsigned short* __restrict__ xbf,
                                            unsigned short* __restrict__ w1t,
                                            float* __restrict__ out) {
  __shared__ __align__(16) unsigned char smem[33024];
  int tid = threadIdx.x;
  int bx = blockIdx.x;

  if (bx >= 1536) {
    // ---------- zero out rows [TK_, CAP_): gemm (launched after) overwrites valid ones ----------
    int row = TK_ + (bx - 1536);
    float4 z = {0.f, 0.f, 0.f, 0.f};
    float4* o = (float4*)(out + (size_t)row * DFFN_);
    o[tid] = z;
    o[tid + 256] = z;
    return;
  }

  if (bx < 512) {
    // ---------- router: top-2 expert ids + bf16 cast of x ----------
    float* lwr = (float*)smem;
    for (int i = tid; i < E_ * D_ / 4; i += 256)
      ((float4*)lwr)[i] = ((const float4*)wr)[i];
    __syncthreads();
    int wave = tid >> 6, lane = tid & 63;

    for (int tk = 0; tk < 4; ++tk) {
      int t = bx * 16 + wave * 4 + tk;
      double acc[E_];
#pragma unroll
      for (int e = 0; e < E_; ++e) acc[e] = 0.0;
      const float4* xr = (const float4*)(x + (size_t)t * D_);
      ushort4* xw = (ushort4*)(xbf + (size_t)t * D_);
#pragma unroll
      for (int j = 0; j < 4; ++j) {
        float4 v = xr[j * 64 + lane];
        ushort4 o;
        o.x = f2bf(v.x); o.y = f2bf(v.y); o.z = f2bf(v.z); o.w = f2bf(v.w);
        xw[j * 64 + lane] = o;
        int dbase = j * 256 + lane * 4;
#pragma unroll
        for (int e = 0; e < E_; ++e) {
          float4 w = *(const float4*)(lwr + e * D_ + dbase);
          acc[e] += (double)v.x * w.x + (double)v.y * w.y +
                    (double)v.z * w.z + (double)v.w * w.w;
        }
      }
#pragma unroll
      for (int e = 0; e < E_; ++e) {
        acc[e] += __shfl_xor(acc[e], 1, 64);
        acc[e] += __shfl_xor(acc[e], 2, 64);
        acc[e] += __shfl_xor(acc[e], 4, 64);
      }
      double s01 = (lane & 1) ? acc[1] : acc[0];
      double s23 = (lane & 1) ? acc[3] : acc[2];
      double s45 = (lane & 1) ? acc[5] : acc[4];
      double s67 = (lane & 1) ? acc[7] : acc[6];
      double t0 = (lane & 2) ? s23 : s01;
      double t1 = (lane & 2) ? s67 : s45;
      double u  = (lane & 4) ? t1 : t0;
      u += __shfl_xor(u, 8, 64);
      u += __shfl_xor(u, 16, 64);
      u += __shfl_xor(u, 32, 64);
      double lg[E_];
#pragma unroll
      for (int e = 0; e < E_; ++e) lg[e] = __shfl(u, e, 64);
      int e1 = 0; double b1 = lg[0];
#pragma unroll
      for (int e = 1; e < E_; ++e) if (lg[e] > b1) { b1 = lg[e]; e1 = e; }
      int e2 = (e1 == 0) ? 1 : 0; double b2 = lg[e2];
#pragma unroll
      for (int e = 0; e < E_; ++e) if (e != e1 && lg[e] > b2) { b2 = lg[e]; e2 = e; }
      if (lane == 0) {
        sel[2 * t]     = e1;
        sel[2 * t + 1] = e2;
      }
    }
  } else {
    // ---------- w1conv: w1 [d][16384] f32 -> w1t [n][1024] bf16 ----------
    typedef unsigned short row258[258];
    row258* lds = (row258*)smem;
    int b = bx - 512;
    int n0 = (b & 63) * 256, d0 = (b >> 6) * 64;
    int rIn = tid >> 6, c4 = tid & 63;
#pragma unroll
    for (int p = 0; p < 16; ++p) {
      int row = p * 4 + rIn;
      float4 v = *(const float4*)(w1 + (size_t)(d0 + row) * 16384 + n0 + c4 * 4);
      lds[row][c4 * 4 + 0] = f2bf(v.x);
      lds[row][c4 * 4 + 1] = f2bf(v.y);
      lds[row][c4 * 4 + 2] = f2bf(v.z);
      lds[row][c4 * 4 + 3] = f2bf(v.w);
    }
    __syncthreads();
    int d2 = (tid & 15) * 4, nn = tid >> 4;
#pragma unroll
    for (int q = 0; q < 16; ++q) {
      int n = q * 16 + nn;
      ushort4 o;
      o.x = lds[d2 + 0][n]; o.y = lds[d2 + 1][n];
      o.z = lds[d2 + 2][n]; o.w = lds[d2 + 3][n];
      *(ushort4*)(w1t + (size_t)(n0 + n) * 1024 + d0 + d2) = o;
    }
  }
}

// ---------------- 2. full counting-sort in ONE block (1024 threads) ----------------
// tile word: bits0-14 rowBase | bits15-17 e | bit18 is128 | bits19-27 mValid
__global__ __launch_bounds__(1024) void k_sort(const int* __restrict__ sel,
                                               int* __restrict__ totals,
                                               int* __restrict__ tiles,
                                               int* __restrict__ row_src) {
  __shared__ int spanCnt[1024][9];   // [t][e] span histogram / phase-3 running counter
  __shared__ int spanOff[1024][9];   // [t][e] prefix of spans within chunk
  __shared__ int chunkOff[64][8];    // [c][e] prefix of chunks within expert
  __shared__ int scnt[8];            // tokens per expert
  __shared__ int scum[9];            // padded cumulative (cum_p)
  __shared__ int lsel[16384];
  int t = threadIdx.x;
  int base = t * 16;

  // phase 1: load + span histogram
#pragma unroll
  for (int e = 0; e < 8; ++e) spanCnt[t][e] = 0;
#pragma unroll
  for (int j = 0; j < 16; ++j) {
    int e = sel[base + j];
    lsel[base + j] = e;
    spanCnt[t][e] += 1;
  }
  __syncthreads();

  // phase 2a: prefix over 16 spans per (chunk, expert)
  if (t < 512) {
    int c = t >> 3, e = t & 7;
    int run = 0;
#pragma unroll
    for (int s = 0; s < 16; ++s) {
      spanOff[c * 16 + s][e] = run;
      run += spanCnt[c * 16 + s][e];
    }
    chunkOff[c][e] = run;  // temporarily chunk count
  }
  __syncthreads();

  // phase 2b: prefix over 64 chunks per expert
  if (t < 8) {
    int run = 0;
    for (int c = 0; c < 64; ++c) {
      int v = chunkOff[c][t];
      chunkOff[c][t] = run;
      run += v;
    }
    scnt[t] = run;
  }
  __syncthreads();

  // phase 2c: cum_p, tile table, totals
  if (t == 0) {
    int cp = 0, nt = 0;
    scum[0] = 0;
    for (int e = 0; e < E_; ++e) {
      int cnt = scnt[e];
      int gs = (cnt + 63) / 64 * 64;
      int r = 0;
      while (r < gs) {
        int m = (gs - r >= 128) ? 128 : 64;
        int mv = cnt - r;
        if (mv < 0) mv = 0;
        if (mv > m) mv = m;
        tiles[nt++] = (cp + r) | (e << 15) | ((m == 128) ? (1 << 18) : 0) | (mv << 19);
        r += m;
      }
      cp += gs;
      scum[e + 1] = cp;
    }
    totals[0] = cp;
    totals[1] = nt;
  }
  __syncthreads();

  // phase 2d: padding rows -> -1
  for (int e = 0; e < E_; ++e) {
    int s = scum[e] + scnt[e], en = scum[e + 1];
    for (int i = s + t; i < en; i += 1024) row_src[i] = -1;
  }
  for (int i = scum[8] + t; i < CAP_ + 64; i += 1024) row_src[i] = -1;

  // phase 3: stable ranks (reuse spanCnt as running local counter)
#pragma unroll
  for (int e = 0; e < 8; ++e) spanCnt[t][e] = 0;
#pragma unroll
  for (int j = 0; j < 16; ++j) {
    int e = lsel[base + j];
    int dst = scum[e] + chunkOff[t >> 4][e] + spanOff[t][e] + spanCnt[t][e];
    spanCnt[t][e] += 1;
    row_src[dst] = (base + j) >> 1;
  }
}

// ---------------- 3. grouped GEMM: m97 structure (128x128, BK=64, 32KiB, 4 waves) ----------------
#define READ_A(dst, KS)                                                         \
  {                                                                             \
    const unsigned short* p_ = As + (wr * 64 + lane15) * 64;                    \
    int co_ = (((KS) * 64 + g16) ^ swz) >> 1;                                   \
    _Pragma("unroll") for (int mi = 0; mi < 4; ++mi)                            \
      dst[mi] = *(const bf16x8*)(p_ + mi * 1024 + co_);                         \
  }

#define READ_B(dst, KS)                                                         \
  {                                                                             \
    const unsigned short* p_ = Bs + (wc * 64 + lane15) * 64;                    \
    int co_ = (((KS) * 64 + g16) ^ swz) >> 1;                                   \
    _Pragma("unroll") for (int ni = 0; ni < 4; ++ni)                            \
      dst[ni] = *(const bf16x8*)(p_ + ni * 1024 + co_);                         \
  }

#define MFMA16(AV, BV)                                                          \
  __builtin_amdgcn_s_setprio(1);                                                \
  _Pragma("unroll") for (int mi = 0; mi < 4; ++mi)                              \
    _Pragma("unroll") for (int ni = 0; ni < 4; ++ni)                            \
      acc[mi][ni] = __builtin_amdgcn_mfma_f32_16x16x32_bf16(                    \
          AV[mi], BV[ni], acc[mi][ni], 0, 0, 0);                                \
  __builtin_amdgcn_s_setprio(0);

__global__ __launch_bounds__(256, 4) void k_gemm(const unsigned short* __restrict__ xbf,
                                                 const unsigned short* __restrict__ w1t,
                                                 const int* __restrict__ row_src,
                                                 const int* __restrict__ tiles,
                                                 const int* __restrict__ totals,
                                                 float* __restrict__ out) {
  // T1: bijective XCD chunking; mtile-major inside a chunk.
  int P = blockIdx.y * MAXT_ + blockIdx.x;
  int L = (P & 7) * (MAXT_ * 16 / 8) + (P >> 3);
  int mtile = L >> 4, ny = L & 15;
  if (mtile >= totals[1]) return;

  int info = tiles[mtile];
  int rowBase = info & 0x7FFF;
  int e = (info >> 15) & 7;
  int mLimit = ((info >> 18) & 1) ? 128 : 64;
  int mValid = (info >> 19) & 0x1FF;

  __shared__ unsigned short As[128 * 64];
  __shared__ unsigned short Bs[128 * 64];

  int tid = threadIdx.x, wave = tid >> 6, lane = tid & 63;
  int lane15 = lane & 15;
  int g16 = (lane >> 4) * 16;          // byte offset of k-group
  int swz = (lane15 & 7) << 4;         // read-side swizzle (bytes)
  int wr = wave >> 1, wc = wave & 1;

  // staging geometry: 8 lanes/row, 16B each; inverse-swizzled source column
  int rr = tid >> 3;                           // 0..31 row within 32-row region
  int co = ((tid & 7) ^ (rr & 7)) << 3;        // elem offset (inverse swizzle)
  int woff = (tid >> 6) << 9;                  // wave*512 elems LDS dst offset

  // gathered A sources (one per 32-row region), clamped both ways
  const unsigned short* Asrc[4];
#pragma unroll
  for (int q = 0; q < 4; ++q) {
    int sr = row_src[rowBase + q * 32 + rr];
    if ((unsigned)sr >= (unsigned)T_) sr = 0;  // padding rows masked at epilogue
    Asrc[q] = xbf + (size_t)sr * D_ + co;
  }
  const unsigned short* Bg = w1t + ((size_t)e * DFFN_ + (size_t)ny * 128) * D_;

  f32x4 acc[4][4];
#pragma unroll
  for (int i = 0; i < 4; ++i)
#pragma unroll
    for (int j = 0; j < 4; ++j) acc[i][j] = (f32x4){0.f, 0.f, 0.f, 0.f};

  for (int t = 0; t < 16; ++t) {
    int k0 = t * 64;
#pragma unroll
    for (int q = 0; q < 4; ++q)
      __builtin_amdgcn_global_load_lds(
          (const __attribute__((address_space(1))) void*)(Asrc[q] + k0),
          (__attribute__((address_space(3))) void*)(As + q * 2048 + woff), 16, 0, 0);
#pragma unroll
    for (int q = 0; q < 4; ++q)
      __builtin_amdgcn_global_load_lds(
          (const __attribute__((address_space(1))) void*)(Bg + (size_t)(q * 32 + rr) * D_ + k0 + co),
          (__attribute__((address_space(3))) void*)(Bs + q * 2048 + woff), 16, 0, 0);
    __syncthreads();   // drains vmcnt+lgkm then barrier (m97 structure)

    bf16x8 a0[4], b0[4], a1[4], b1[4];
    READ_A(a0, 0);
    READ_B(b0, 0);
    MFMA16(a0, b0);
    READ_A(a1, 1);
    READ_B(b1, 1);
    MFMA16(a1, b1);
    __syncthreads();   // all waves done reading before next tile overwrites
  }

  // epilogue: C layout col=lane&15, row=(lane>>4)*4+q; mask padding rows to 0
#pragma unroll
  for (int mi = 0; mi < 4; ++mi) {
    int mrow = wr * 64 + mi * 16;
    if (mrow >= mLimit) continue;
    int rbase = mrow + (lane >> 4) * 4;
#pragma unroll
    for (int ni = 0; ni < 4; ++ni) {
      int col = ny * 128 + wc * 64 + ni * 16 + lane15;
      f32x4 v = acc[mi][ni];
#pragma unroll
      for (int q = 0; q < 4; ++q) {
        float val = (rbase + q < mValid) ? v[q] : 0.0f;
        out[(size_t)(rowBase + rbase + q) * DFFN_ + col] = val;
      }
    }
  }
}

extern "C" void kernel_launch(void* const* d_in, const int* in_sizes, int n_in,
                              void* d_out, int out_size, void* d_ws, size_t ws_size,
                              hipStream_t stream) {
  const float* x  = (const float*)d_in[0];
  const float* wr = (const float*)d_in[1];
  const float* w1 = (const float*)d_in[2];
  float* out = (float*)d_out;
  char* ws = (char*)d_ws;

  int* sel     = (int*)(ws + WS_SEL);
  int* totals  = (int*)(ws + WS_TOTALS);
  int* tiles   = (int*)(ws + WS_TILES);
  int* row_src = (int*)(ws + WS_ROWSRC);
  unsigned short* xbf = (unsigned short*)(ws + WS_XBF);
  unsigned short* w1t = (unsigned short*)(ws + WS_W1T);

  k_rw<<<2048, 256, 0, stream>>>(x, wr, w1, sel, xbf, w1t, out);
  k_sort<<<1, 1024, 0, stream>>>(sel, totals, tiles, row_src);
  k_gemm<<<dim3(MAXT_, 16), 256, 0, stream>>>(xbf, w1t, row_src, tiles, totals, out);
}

// Round 11
// 126.632 us; speedup vs baseline: 1.5759x; 1.2384x over previous
//
#include <hip/hip_runtime.h>
#include <stdint.h>

#define E_       8
#define D_       1024
#define DFFN_    2048
#define T_       8192
#define TK_      16384
#define CAP_     16896
#define MAXT_    144       // max 128-row tiles

// workspace layout (bytes)
#define WS_SEL      0u          // TK_*4
#define WS_TOTALS   0x10200u    // [0]=total_padded [1]=nTiles
#define WS_TILES    0x11300u    // MAXT_*4
#define WS_ROWSRC   0x12000u    // (CAP_+64)*4
#define WS_XBF      0x23000u    // T_*1024*2 = 16777216
#define WS_W1T      (0x23000u + 34603008u)              // 16384*1024*2 = 33554432
#define WS_H        (0x23000u + 34603008u + 33554432u)  // 512*8*4 router histograms

typedef __bf16 bf16x8 __attribute__((ext_vector_type(8)));
typedef float  f32x4  __attribute__((ext_vector_type(4)));

__device__ __forceinline__ unsigned short f2bf(float f) {
  union { float f; uint32_t u; } v; v.f = f;
  return (unsigned short)((v.u + 0x7fffu + ((v.u >> 16) & 1u)) >> 16);
}

// ---- 1. fused: router (0..511, + per-block histogram) + w1conv (512..1535) + tail zero ----
__global__ __launch_bounds__(256) void k_rw(const float* __restrict__ x,
                                            const float* __restrict__ wr,
                                            const float* __restrict__ w1,
                                            int* __restrict__ sel,
                                            int* __restrict__ h,
                                            unsigned short* __restrict__ xbf,
                                            unsigned short* __restrict__ w1t,
                                            float* __restrict__ out) {
  __shared__ __align__(16) unsigned char smem[33024];
  int tid = threadIdx.x;
  int bx = blockIdx.x;

  if (bx >= 1536) {
    // ---------- zero out rows [TK_, CAP_): gemm (launched after) overwrites valid ones ----------
    int row = TK_ + (bx - 1536);
    float4 z = {0.f, 0.f, 0.f, 0.f};
    float4* o = (float4*)(out + (size_t)row * DFFN_);
    o[tid] = z;
    o[tid + 256] = z;
    return;
  }

  if (bx < 512) {
    // ---------- router: top-2 expert ids + bf16 cast of x + 32-entry histogram ----------
    float* lwr = (float*)smem;
    int* selL = (int*)(smem + 32768);    // 32 ints
    for (int i = tid; i < E_ * D_ / 4; i += 256)
      ((float4*)lwr)[i] = ((const float4*)wr)[i];
    __syncthreads();
    int wave = tid >> 6, lane = tid & 63;

    for (int tk = 0; tk < 4; ++tk) {
      int t = bx * 16 + wave * 4 + tk;
      double acc[E_];
#pragma unroll
      for (int e = 0; e < E_; ++e) acc[e] = 0.0;
      const float4* xr = (const float4*)(x + (size_t)t * D_);
      ushort4* xw = (ushort4*)(xbf + (size_t)t * D_);
#pragma unroll
      for (int j = 0; j < 4; ++j) {
        float4 v = xr[j * 64 + lane];
        ushort4 o;
        o.x = f2bf(v.x); o.y = f2bf(v.y); o.z = f2bf(v.z); o.w = f2bf(v.w);
        xw[j * 64 + lane] = o;
        int dbase = j * 256 + lane * 4;
#pragma unroll
        for (int e = 0; e < E_; ++e) {
          float4 w = *(const float4*)(lwr + e * D_ + dbase);
          acc[e] += (double)v.x * w.x + (double)v.y * w.y +
                    (double)v.z * w.z + (double)v.w * w.w;
        }
      }
#pragma unroll
      for (int e = 0; e < E_; ++e) {
        acc[e] += __shfl_xor(acc[e], 1, 64);
        acc[e] += __shfl_xor(acc[e], 2, 64);
        acc[e] += __shfl_xor(acc[e], 4, 64);
      }
      double s01 = (lane & 1) ? acc[1] : acc[0];
      double s23 = (lane & 1) ? acc[3] : acc[2];
      double s45 = (lane & 1) ? acc[5] : acc[4];
      double s67 = (lane & 1) ? acc[7] : acc[6];
      double t0 = (lane & 2) ? s23 : s01;
      double t1 = (lane & 2) ? s67 : s45;
      double u  = (lane & 4) ? t1 : t0;
      u += __shfl_xor(u, 8, 64);
      u += __shfl_xor(u, 16, 64);
      u += __shfl_xor(u, 32, 64);
      double lg[E_];
#pragma unroll
      for (int e = 0; e < E_; ++e) lg[e] = __shfl(u, e, 64);
      int e1 = 0; double b1 = lg[0];
#pragma unroll
      for (int e = 1; e < E_; ++e) if (lg[e] > b1) { b1 = lg[e]; e1 = e; }
      int e2 = (e1 == 0) ? 1 : 0; double b2 = lg[e2];
#pragma unroll
      for (int e = 0; e < E_; ++e) if (e != e1 && lg[e] > b2) { b2 = lg[e]; e2 = e; }
      if (lane == 0) {
        sel[2 * t]     = e1;
        sel[2 * t + 1] = e2;
        selL[wave * 8 + tk * 2]     = e1;
        selL[wave * 8 + tk * 2 + 1] = e2;
      }
    }
    __syncthreads();
    if (tid < E_) {
      int c = 0;
#pragma unroll
      for (int i = 0; i < 32; ++i) c += (selL[i] == tid);
      h[bx * E_ + tid] = c;
    }
  } else {
    // ---------- w1conv: w1 [d][16384] f32 -> w1t [n][1024] bf16 ----------
    typedef unsigned short row258[258];
    row258* lds = (row258*)smem;
    int b = bx - 512;
    int n0 = (b & 63) * 256, d0 = (b >> 6) * 64;
    int rIn = tid >> 6, c4 = tid & 63;
#pragma unroll
    for (int p = 0; p < 16; ++p) {
      int row = p * 4 + rIn;
      float4 v = *(const float4*)(w1 + (size_t)(d0 + row) * 16384 + n0 + c4 * 4);
      lds[row][c4 * 4 + 0] = f2bf(v.x);
      lds[row][c4 * 4 + 1] = f2bf(v.y);
      lds[row][c4 * 4 + 2] = f2bf(v.z);
      lds[row][c4 * 4 + 3] = f2bf(v.w);
    }
    __syncthreads();
    int d2 = (tid & 15) * 4, nn = tid >> 4;
#pragma unroll
    for (int q = 0; q < 16; ++q) {
      int n = q * 16 + nn;
      ushort4 o;
      o.x = lds[d2 + 0][n]; o.y = lds[d2 + 1][n];
      o.z = lds[d2 + 2][n]; o.w = lds[d2 + 3][n];
      *(ushort4*)(w1t + (size_t)(n0 + n) * 1024 + d0 + d2) = o;
    }
  }
}

// ---- 2. parallel placement: 65 blocks. 0..63 rank+scatter their 256-entry chunk via
//         wave64 ballot; block 64 writes tile table + padding. No atomics, disjoint writes.
// tile word: bits0-14 rowBase | bits15-17 e | bit18 is128 | bits19-27 mValid
__global__ __launch_bounds__(256) void k_place(const int* __restrict__ sel,
                                               const int* __restrict__ h,
                                               int* __restrict__ totals,
                                               int* __restrict__ tiles,
                                               int* __restrict__ row_src) {
  __shared__ int hL[512][8];     // router-block histograms
  __shared__ int preSC[64][8];   // exclusive prefix of 8-rb super-chunks per expert
  __shared__ int scnt[8];
  __shared__ int scum[9];
  int tid = threadIdx.x;
  int c = blockIdx.x;

  // load h (16KB, coalesced)
  for (int i = tid; i < 512 * 8 / 4; i += 256)
    ((int4*)&hL[0][0])[i] = ((const int4*)h)[i];
  __syncthreads();

  // super-chunk sums: preSC[sc][e] = sum over rb in [8sc, 8sc+8)
  for (int idx = tid; idx < 512; idx += 256) {
    int sc = idx >> 3, e = idx & 7;
    int s = 0;
#pragma unroll
    for (int i = 0; i < 8; ++i) s += hL[sc * 8 + i][e];
    preSC[sc][e] = s;
  }
  __syncthreads();

  // in-place exclusive prefix over 64 super-chunks, per expert
  if (tid < 8) {
    int run = 0;
    for (int sc = 0; sc < 64; ++sc) {
      int v = preSC[sc][tid];
      preSC[sc][tid] = run;
      run += v;
    }
    scnt[tid] = run;
  }
  __syncthreads();
  if (tid == 0) {
    int cp = 0;
    scum[0] = 0;
    for (int e = 0; e < E_; ++e) {
      cp += (scnt[e] + 63) / 64 * 64;
      scum[e + 1] = cp;
    }
  }
  __syncthreads();

  if (c < 64) {
    // rank + scatter: chunk c covers sel[c*256 .. c*256+255], super-chunk index == c
    int j = tid;
    int e = sel[c * 256 + j];
    int w = j >> 6;                     // wave 0..3 == router-blocks 8c+2w, 8c+2w+1
    int partial = 0;
    for (int i = 0; i < 2 * w; ++i) partial += hL[c * 8 + i][e];
    unsigned long long below = ((1ULL << (j & 63)) - 1ULL);
    int rank = 0;
#pragma unroll
    for (int ee = 0; ee < 8; ++ee) {
      unsigned long long m = __ballot(e == ee);
      if (ee == e) rank = __popcll(m & below);
    }
    int dst = scum[e] + preSC[c][e] + partial + rank;
    row_src[dst] = (c * 256 + j) >> 1;
  } else {
    // block 64: tile table, totals, padding fills
    if (tid == 0) {
      int nt = 0;
      for (int e = 0; e < E_; ++e) {
        int cnt = scnt[e];
        int cp = scum[e];
        int gs = scum[e + 1] - cp;
        int r = 0;
        while (r < gs) {
          int m = (gs - r >= 128) ? 128 : 64;
          int mv = cnt - r;
          if (mv < 0) mv = 0;
          if (mv > m) mv = m;
          tiles[nt++] = (cp + r) | (e << 15) | ((m == 128) ? (1 << 18) : 0) | (mv << 19);
          r += m;
        }
      }
      totals[0] = scum[8];
      totals[1] = nt;
    }
    for (int e = 0; e < E_; ++e) {
      int s = scum[e] + scnt[e], en = scum[e + 1];
      for (int i = s + tid; i < en; i += 256) row_src[i] = -1;
    }
    for (int i = scum[8] + tid; i < CAP_ + 64; i += 256) row_src[i] = -1;
  }
}

// ---------------- 3. grouped GEMM: m97 structure (128x128, BK=64, 32KiB, 4 waves) ----------------
#define READ_A(dst, KS)                                                         \
  {                                                                             \
    const unsigned short* p_ = As + (wr * 64 + lane15) * 64;                    \
    int co_ = (((KS) * 64 + g16) ^ swz) >> 1;                                   \
    _Pragma("unroll") for (int mi = 0; mi < 4; ++mi)                            \
      dst[mi] = *(const bf16x8*)(p_ + mi * 1024 + co_);                         \
  }

#define READ_B(dst, KS)                                                         \
  {                                                                             \
    const unsigned short* p_ = Bs + (wc * 64 + lane15) * 64;                    \
    int co_ = (((KS) * 64 + g16) ^ swz) >> 1;                                   \
    _Pragma("unroll") for (int ni = 0; ni < 4; ++ni)                            \
      dst[ni] = *(const bf16x8*)(p_ + ni * 1024 + co_);                         \
  }

#define MFMA16(AV, BV)                                                          \
  __builtin_amdgcn_s_setprio(1);                                                \
  _Pragma("unroll") for (int mi = 0; mi < 4; ++mi)                              \
    _Pragma("unroll") for (int ni = 0; ni < 4; ++ni)                            \
      acc[mi][ni] = __builtin_amdgcn_mfma_f32_16x16x32_bf16(                    \
          AV[mi], BV[ni], acc[mi][ni], 0, 0, 0);                                \
  __builtin_amdgcn_s_setprio(0);

__global__ __launch_bounds__(256, 4) void k_gemm(const unsigned short* __restrict__ xbf,
                                                 const unsigned short* __restrict__ w1t,
                                                 const int* __restrict__ row_src,
                                                 const int* __restrict__ tiles,
                                                 const int* __restrict__ totals,
                                                 float* __restrict__ out) {
  // T1: bijective XCD chunking; mtile-major inside a chunk.
  int P = blockIdx.y * MAXT_ + blockIdx.x;
  int L = (P & 7) * (MAXT_ * 16 / 8) + (P >> 3);
  int mtile = L >> 4, ny = L & 15;
  if (mtile >= totals[1]) return;

  int info = tiles[mtile];
  int rowBase = info & 0x7FFF;
  int e = (info >> 15) & 7;
  int mLimit = ((info >> 18) & 1) ? 128 : 64;
  int mValid = (info >> 19) & 0x1FF;

  __shared__ unsigned short As[128 * 64];
  __shared__ unsigned short Bs[128 * 64];

  int tid = threadIdx.x, wave = tid >> 6, lane = tid & 63;
  int lane15 = lane & 15;
  int g16 = (lane >> 4) * 16;          // byte offset of k-group
  int swz = (lane15 & 7) << 4;         // read-side swizzle (bytes)
  int wr = wave >> 1, wc = wave & 1;

  // staging geometry: 8 lanes/row, 16B each; inverse-swizzled source column
  int rr = tid >> 3;                           // 0..31 row within 32-row region
  int co = ((tid & 7) ^ (rr & 7)) << 3;        // elem offset (inverse swizzle)
  int woff = (tid >> 6) << 9;                  // wave*512 elems LDS dst offset

  // gathered A sources (one per 32-row region), clamped both ways
  const unsigned short* Asrc[4];
#pragma unroll
  for (int q = 0; q < 4; ++q) {
    int sr = row_src[rowBase + q * 32 + rr];
    if ((unsigned)sr >= (unsigned)T_) sr = 0;  // padding rows masked at epilogue
    Asrc[q] = xbf + (size_t)sr * D_ + co;
  }
  const unsigned short* Bg = w1t + ((size_t)e * DFFN_ + (size_t)ny * 128) * D_;

  f32x4 acc[4][4];
#pragma unroll
  for (int i = 0; i < 4; ++i)
#pragma unroll
    for (int j = 0; j < 4; ++j) acc[i][j] = (f32x4){0.f, 0.f, 0.f, 0.f};

  for (int t = 0; t < 16; ++t) {
    int k0 = t * 64;
#pragma unroll
    for (int q = 0; q < 4; ++q)
      __builtin_amdgcn_global_load_lds(
          (const __attribute__((address_space(1))) void*)(Asrc[q] + k0),
          (__attribute__((address_space(3))) void*)(As + q * 2048 + woff), 16, 0, 0);
#pragma unroll
    for (int q = 0; q < 4; ++q)
      __builtin_amdgcn_global_load_lds(
          (const __attribute__((address_space(1))) void*)(Bg + (size_t)(q * 32 + rr) * D_ + k0 + co),
          (__attribute__((address_space(3))) void*)(Bs + q * 2048 + woff), 16, 0, 0);
    __syncthreads();   // drains vmcnt+lgkm then barrier (m97 structure)

    bf16x8 a0[4], b0[4], a1[4], b1[4];
    READ_A(a0, 0);
    READ_B(b0, 0);
    MFMA16(a0, b0);
    READ_A(a1, 1);
    READ_B(b1, 1);
    MFMA16(a1, b1);
    __syncthreads();   // all waves done reading before next tile overwrites
  }

  // epilogue: C layout col=lane&15, row=(lane>>4)*4+q; mask padding rows to 0
#pragma unroll
  for (int mi = 0; mi < 4; ++mi) {
    int mrow = wr * 64 + mi * 16;
    if (mrow >= mLimit) continue;
    int rbase = mrow + (lane >> 4) * 4;
#pragma unroll
    for (int ni = 0; ni < 4; ++ni) {
      int col = ny * 128 + wc * 64 + ni * 16 + lane15;
      f32x4 v = acc[mi][ni];
#pragma unroll
      for (int q = 0; q < 4; ++q) {
        float val = (rbase + q < mValid) ? v[q] : 0.0f;
        out[(size_t)(rowBase + rbase + q) * DFFN_ + col] = val;
      }
    }
  }
}

extern "C" void kernel_launch(void* const* d_in, const int* in_sizes, int n_in,
                              void* d_out, int out_size, void* d_ws, size_t ws_size,
                              hipStream_t stream) {
  const float* x  = (const float*)d_in[0];
  const float* wr = (const float*)d_in[1];
  const float* w1 = (const float*)d_in[2];
  float* out = (float*)d_out;
  char* ws = (char*)d_ws;

  int* sel     = (int*)(ws + WS_SEL);
  int* totals  = (int*)(ws + WS_TOTALS);
  int* tiles   = (int*)(ws + WS_TILES);
  int* row_src = (int*)(ws + WS_ROWSRC);
  int* h       = (int*)(ws + WS_H);
  unsigned short* xbf = (unsigned short*)(ws + WS_XBF);
  unsigned short* w1t = (unsigned short*)(ws + WS_W1T);

  k_rw<<<2048, 256, 0, stream>>>(x, wr, w1, sel, h, xbf, w1t, out);
  k_place<<<65, 256, 0, stream>>>(sel, h, totals, tiles, row_src);
  k_gemm<<<dim3(MAXT_, 16), 256, 0, stream>>>(xbf, w1t, row_src, tiles, totals, out);
}